// Round 11
// baseline (821.201 us; speedup 1.0000x reference)
//
#include <hip/hip_runtime.h>
#include <math.h>

#define H 64
#define W 64
#define HW 4096
#define CH 128
#define CIN 256
#define COUT 384
#define KDIM 1152
#define NB 4

typedef _Float16 f16x8 __attribute__((ext_vector_type(8)));
typedef float f32x4 __attribute__((ext_vector_type(4)));

__device__ __forceinline__ void gl_lds16(const _Float16* g, _Float16* l) {
    __builtin_amdgcn_global_load_lds(
        (const __attribute__((address_space(1))) unsigned int*)(g),
        (__attribute__((address_space(3))) unsigned int*)(l), 16, 0, 0);
}

// ---------------- copy former+latter passthrough (float4) ----------------
__global__ void copy_passthrough(const float4* __restrict__ x, float4* __restrict__ out) {
    int idx = blockIdx.x * blockDim.x + threadIdx.x; // over NB*CIN*HW/4
    if (idx >= NB * CIN * HW / 4) return;
    int b = idx / (CIN * HW / 4);
    int rem = idx - b * (CIN * HW / 4);
    out[(size_t)b * (COUT * HW / 4) + rem] = x[idx];
}

// ---------------- im2col of former -> P (HW x KDIM, f16), z = sample in pair ----------------
__global__ void build_patches_f16(const float* __restrict__ x, _Float16* __restrict__ P, int b0) {
    int idx8 = blockIdx.x * blockDim.x + threadIdx.x; // over HW*144
    if (idx8 >= HW * 144) return;
    const float* former = x + (size_t)(b0 + blockIdx.z) * CIN * HW;
    _Float16* Pz = P + (size_t)blockIdx.z * HW * KDIM;
    int i = idx8 / 144, k0 = (idx8 - i * 144) * 8;
    int iy = i >> 6, ix = i & 63;
    f16x8 v8;
    #pragma unroll
    for (int u = 0; u < 8; ++u) {
        int k = k0 + u;
        int c = k / 9, q = k - c * 9;
        int dy = q / 3, dx = q - dy * 3;
        int y = iy + dy - 1, xx = ix + dx - 1;
        float v = 0.f;
        if ((unsigned)y < H && (unsigned)xx < W) v = former[c * HW + y * W + xx];
        v8[u] = (_Float16)v;
    }
    *(f16x8*)(Pz + (size_t)i * KDIM + k0) = v8;
}

// ---------------- normalized latter windows -> WN (f16), md = {mm, mm*den} ----------------
__global__ void build_winn_f16(const float* __restrict__ x, const float* __restrict__ mask,
                               const int* __restrict__ mask_thred_p,
                               _Float16* __restrict__ WN, float2* __restrict__ md, int b0) {
    int b = b0 + blockIdx.z;
    const float* latter = x + (size_t)b * CIN * HW + (size_t)CH * HW;
    const float* maskb = mask + (size_t)b * HW;
    _Float16* WNz = WN + (size_t)blockIdx.z * HW * KDIM;
    float2* mdz = md + (size_t)blockIdx.z * HW;
    int j = blockIdx.x;               // patch index (row-major)
    int y0 = j >> 6, x0 = j & 63;
    __shared__ float red[256];
    float vals[8];
    float ss = 0.f;
    int k0 = threadIdx.x * 8;
    bool act = (threadIdx.x < 144);
    if (act) {
        #pragma unroll
        for (int u = 0; u < 8; ++u) {
            int k = k0 + u;
            int c = k / 9, q = k - c * 9;
            int dy = q / 3, dx = q - dy * 3;
            int y = y0 + dy - 1, xx = x0 + dx - 1;
            float v = 0.f;
            if ((unsigned)y < H && (unsigned)xx < W) v = latter[c * HW + y * W + xx];
            vals[u] = v;
            ss += v * v;
        }
    }
    red[threadIdx.x] = ss;
    __syncthreads();
    for (int s = 128; s > 0; s >>= 1) {
        if (threadIdx.x < s) red[threadIdx.x] += red[threadIdx.x + s];
        __syncthreads();
    }
    float d = fmaxf(sqrtf(red[0]), 1e-4f);
    float inv = 1.f / d;
    if (act) {
        f16x8 w8;
        #pragma unroll
        for (int u = 0; u < 8; ++u) w8[u] = (_Float16)(vals[u] * inv);
        *(f16x8*)(WNz + (size_t)j * KDIM + k0) = w8;
    }
    if (threadIdx.x == 0) {
        float s = 0.f;
        for (int q = 0; q < 9; ++q) {
            int dy = q / 3, dx = q - dy * 3;
            int y = y0 + dy - 1, xx = x0 + dx - 1;
            if ((unsigned)y < H && (unsigned)xx < W) s += maskb[y * W + xx];
        }
        float mmean = s / 9.f;
        float thr = (float)mask_thred_p[0] / 9.f;
        float m = (mmean <= thr) ? 1.f : 0.f;
        mdz[j] = make_float2(m, m * d);
    }
}

// ---------------- GEMM1: 256x256 tile, BK=64, 8-phase counted-vmcnt (r4-measured-best variant) ----------------
__launch_bounds__(512, 2)
__global__ void gemm1_8ph(const _Float16* __restrict__ A0, const _Float16* __restrict__ B0,
                          _Float16* __restrict__ C0) {
    const int K = KDIM;
    const int NT = KDIM / 64;     // 18 K-tiles
    const _Float16* A = A0 + (size_t)blockIdx.z * HW * KDIM;
    const _Float16* B = B0 + (size_t)blockIdx.z * HW * KDIM;
    _Float16* C = C0 + (size_t)blockIdx.z * HW * HW;

    extern __shared__ _Float16 lds[];
    _Float16* As = lds;            // [2][2][128][64]
    _Float16* Bs = lds + 32768;    // [2][2][128][64]

    int tid = threadIdx.x;
    int wave = tid >> 6, lane = tid & 63;
    int quad = lane >> 4, lr = lane & 15;
    int wr = wave >> 2, wc = wave & 3;

    int lin = blockIdx.x;
    int wg = (lin & 7) * 32 + (lin >> 3);
    int i0 = (wg >> 4) * 256, j0 = (wg & 15) * 256;

    const _Float16* Ab = A + (size_t)i0 * K;
    const _Float16* Bb = B + (size_t)j0 * K;

    f32x4 acc[8][4];
    #pragma unroll
    for (int f = 0; f < 8; ++f)
        #pragma unroll
        for (int g = 0; g < 4; ++g) acc[f][g] = (f32x4){0.f, 0.f, 0.f, 0.f};

    auto stageA = [&](int d, int h, int v) {
        const _Float16* g = Ab + (size_t)(h * 128) * K + v * 64;
        _Float16* dst = As + d * 16384 + h * 8192;
        #pragma unroll
        for (int l = 0; l < 2; ++l) {
            int slot = tid + l * 512;
            int row = slot >> 3;
            gl_lds16(g + (size_t)row * K + (((slot & 7) ^ (row & 7)) << 3), dst + slot * 8);
        }
    };
    auto stageB = [&](int d, int h, int v) {
        const _Float16* g = Bb + (size_t)(h * 128) * K + v * 64;
        _Float16* dst = Bs + d * 16384 + h * 8192;
        #pragma unroll
        for (int l = 0; l < 2; ++l) {
            int slot = tid + l * 512;
            int row = slot >> 3;
            gl_lds16(g + (size_t)row * K + (((slot & 7) ^ (row & 7)) << 3), dst + slot * 8);
        }
    };

    stageA(0, 0, 0); stageB(0, 1, 0); stageA(0, 1, 0); stageB(0, 0, 0);
    stageA(1, 0, 1); stageB(1, 1, 1);
    asm volatile("s_waitcnt vmcnt(4)" ::: "memory");
    __builtin_amdgcn_s_barrier();
    __builtin_amdgcn_sched_barrier(0);

    for (int u = 0; u < NT; ++u) {
        int d = u & 1;
        #pragma unroll
        for (int ph = 0; ph < 4; ++ph) {
            const int mh = ph >> 1;
            const int nh = (ph == 1 || ph == 2) ? 1 : 0;
            const _Float16* Ah = As + d * 16384 + mh * 8192;
            const _Float16* Bh = Bs + d * 16384 + nh * 8192;
            f16x8 af[4][2], bfr[2][2];
            #pragma unroll
            for (int f = 0; f < 4; ++f)
                #pragma unroll
                for (int ks = 0; ks < 2; ++ks)
                    af[f][ks] = *(const f16x8*)(Ah + (wr * 16 + f * 32 + lr) * 64 +
                                                ((((ks << 2) | quad) ^ (lr & 7)) << 3));
            #pragma unroll
            for (int g = 0; g < 2; ++g)
                #pragma unroll
                for (int ks = 0; ks < 2; ++ks)
                    bfr[g][ks] = *(const f16x8*)(Bh + (wc * 16 + g * 64 + lr) * 64 +
                                                 ((((ks << 2) | quad) ^ (lr & 7)) << 3));
            if (ph == 0)      { if (u + 1 < NT) stageA(d ^ 1, 1, u + 1); }
            else if (ph == 1) { if (u + 1 < NT) stageB(d ^ 1, 0, u + 1); }
            else if (ph == 2) { if (u + 2 < NT) stageA(d, 0, u + 2); }
            else              { if (u + 2 < NT) stageB(d, 1, u + 2); }

            __builtin_amdgcn_s_barrier();
            __builtin_amdgcn_s_setprio(1);
            #pragma unroll
            for (int f = 0; f < 4; ++f)
                #pragma unroll
                for (int g = 0; g < 2; ++g)
                    #pragma unroll
                    for (int ks = 0; ks < 2; ++ks)
                        acc[mh * 4 + f][nh * 2 + g] = __builtin_amdgcn_mfma_f32_16x16x32_f16(
                            af[f][ks], bfr[g][ks], acc[mh * 4 + f][nh * 2 + g], 0, 0, 0);
            __builtin_amdgcn_s_setprio(0);

            if (ph == 3) {
                if (u + 2 < NT)      asm volatile("s_waitcnt vmcnt(4)" ::: "memory");
                else if (u + 1 < NT) asm volatile("s_waitcnt vmcnt(0)" ::: "memory");
                __builtin_amdgcn_sched_barrier(0);
            }
            __builtin_amdgcn_s_barrier();
        }
    }

    #pragma unroll
    for (int f = 0; f < 8; ++f) {
        #pragma unroll
        for (int r = 0; r < 4; ++r) {
            int row = i0 + wr * 16 + f * 32 + quad * 4 + r;
            _Float16* Cr = C + (size_t)row * HW + j0 + wc * 16 + lr;
            #pragma unroll
            for (int g = 0; g < 4; ++g)
                Cr[g * 64] = (_Float16)acc[f][g][r];
        }
    }
}

// ---------------- GEMM2: MFMA f16 NT, 128(M)x64(N) tile, BK=64, full K, f16 out ----------------
// Measured-best for M=1152: 1152 blocks = 4.5/CU -> cross-block overlap (98.5 us).
// 256^2-8ph (119 us, r5) and 128^2 (107.7 us, r10) both measured worse at this shape.
__launch_bounds__(256)
__global__ void gemm2_f16_nt(const _Float16* __restrict__ A0, const _Float16* __restrict__ B0,
                             _Float16* __restrict__ C0, int K, int ldc) {
    const _Float16* A = A0 + (size_t)blockIdx.z * HW * HW;   // WNT_z
    const _Float16* B = B0 + (size_t)blockIdx.z * HW * HW;   // V_z
    _Float16* C = C0 + (size_t)blockIdx.z * HW * HW;         // C2T_z
    __shared__ _Float16 As[128 * 64];
    __shared__ _Float16 Bs[64 * 64];
    int tid = threadIdx.x;
    int wave = tid >> 6, lane = tid & 63;
    int quad = lane >> 4, lr = lane & 15;
    int wr = wave >> 1, wc = wave & 1;
    int i0 = blockIdx.y * 128, j0 = blockIdx.x * 64;

    int r0 = tid >> 3;
    int lk = ((tid & 7) ^ ((tid >> 3) & 7)) * 8;

    f32x4 acc[4][2];
    #pragma unroll
    for (int a = 0; a < 4; ++a)
        #pragma unroll
        for (int b = 0; b < 2; ++b) acc[a][b] = (f32x4){0.f, 0.f, 0.f, 0.f};

    const _Float16* Ab = A + (size_t)i0 * K;
    const _Float16* Bb = B + (size_t)j0 * K;

    int ra[4][2], rb[2][2];
    #pragma unroll
    for (int t = 0; t < 4; ++t) {
        int rowA = wr * 64 + t * 16 + lr;
        #pragma unroll
        for (int s = 0; s < 2; ++s)
            ra[t][s] = rowA * 64 + (((quad + 4 * s) ^ (lr & 7)) * 8);
    }
    #pragma unroll
    for (int t = 0; t < 2; ++t) {
        int rowB = wc * 32 + t * 16 + lr;
        #pragma unroll
        for (int s = 0; s < 2; ++s)
            rb[t][s] = rowB * 64 + (((quad + 4 * s) ^ (lr & 7)) * 8);
    }

    for (int k0 = 0; k0 < K; k0 += 64) {
        __syncthreads();
        #pragma unroll
        for (int j = 0; j < 4; ++j) {
            int row = r0 + j * 32;
            gl_lds16(Ab + (size_t)row * K + k0 + lk, As + (tid + j * 256) * 8);
        }
        #pragma unroll
        for (int j = 0; j < 2; ++j) {
            int row = r0 + j * 32;
            gl_lds16(Bb + (size_t)row * K + k0 + lk, Bs + (tid + j * 256) * 8);
        }
        __syncthreads();
        #pragma unroll
        for (int s = 0; s < 2; ++s) {
            f16x8 af[4], bfr[2];
            #pragma unroll
            for (int mi = 0; mi < 4; ++mi) af[mi] = *(const f16x8*)(As + ra[mi][s]);
            #pragma unroll
            for (int ni = 0; ni < 2; ++ni) bfr[ni] = *(const f16x8*)(Bs + rb[ni][s]);
            #pragma unroll
            for (int mi = 0; mi < 4; ++mi)
                #pragma unroll
                for (int ni = 0; ni < 2; ++ni)
                    acc[mi][ni] = __builtin_amdgcn_mfma_f32_16x16x32_f16(af[mi], bfr[ni], acc[mi][ni], 0, 0, 0);
        }
    }

    #pragma unroll
    for (int mi = 0; mi < 4; ++mi) {
        #pragma unroll
        for (int r = 0; r < 4; ++r) {
            int row = i0 + wr * 64 + mi * 16 + quad * 4 + r;
            _Float16* Cr = C + (size_t)row * ldc + j0 + wc * 32 + lr;
            #pragma unroll
            for (int ni = 0; ni < 2; ++ni)
                Cr[ni * 16] = (_Float16)acc[mi][ni][r];
        }
    }
}

// ---------------- fused diag-conv^2 + softmax, LDS-staged (r3/r4-measured-best) ----------------
__launch_bounds__(512)
__global__ void dconv_softmax(const _Float16* __restrict__ S0, const float2* __restrict__ md0,
                              _Float16* __restrict__ V0) {
    const _Float16* S = S0 + (size_t)blockIdx.z * HW * HW;
    const float2* md = md0 + (size_t)blockIdx.z * HW;
    _Float16* V = V0 + (size_t)blockIdx.z * HW * HW;
    int p = (blockIdx.x & 7) * 512 + (blockIdx.x >> 3);   // XCD-contiguous p ranges
    int tid = threadIdx.x;
    int q0 = tid * 8;

    __shared__ _Float16 Ls[9][HW];     // 73,728 B -> 2 blocks/CU
    __shared__ float wmax[8], wsum[8];

    const int P1 = ((p >> 6) < 63) ? (p + 64) : ((p & 63) + 1);   // valid iff p != 4095
    const int P0 = ((p >> 6) > 0) ? (p - 64) : (4031 + (p & 63)); // valid iff p != 0
    const bool gv1 = (p != 4095), gv2 = (p != 0);

    int rows[9];
    bool rv[9];
    rows[0] = p - 1;  rows[1] = p;  rows[2] = p + 1;
    rows[3] = P1 - 1; rows[4] = P1; rows[5] = P1 + 1;
    rows[6] = P0 - 1; rows[7] = P0; rows[8] = P0 + 1;
    rv[0] = ((unsigned)(p - 1) < HW);
    rv[1] = true;
    rv[2] = ((unsigned)(p + 1) < HW);
    rv[3] = gv1 && ((unsigned)(P1 - 1) < HW);
    rv[4] = gv1;
    rv[5] = gv1 && ((unsigned)(P1 + 1) < HW);
    rv[6] = gv2 && ((unsigned)(P0 - 1) < HW);
    rv[7] = gv2;
    rv[8] = gv2 && ((unsigned)(P0 + 1) < HW);

    #pragma unroll
    for (int s = 0; s < 9; ++s) {
        if (rv[s])
            gl_lds16(S + (size_t)rows[s] * HW + q0, &Ls[s][0] + q0);
    }
    __syncthreads();   // drains vmcnt before barrier

    float D[8] = {0.f, 0.f, 0.f, 0.f, 0.f, 0.f, 0.f, 0.f};

    // ---- group 0 (d2 = 0): cols q0 + d1 ----
    {
        const int cb = q0;
        if (rv[0]) {
            f16x8 v = *(const f16x8*)(&Ls[0][0] + cb);
            #pragma unroll
            for (int u = 1; u < 8; ++u) D[u] += (float)v[u - 1];
            if (cb > 0) D[0] += (float)Ls[0][cb - 1];
        }
        {
            f16x8 v = *(const f16x8*)(&Ls[1][0] + cb);
            #pragma unroll
            for (int u = 0; u < 8; ++u) D[u] += (float)v[u];
        }
        if (rv[2]) {
            f16x8 v = *(const f16x8*)(&Ls[2][0] + cb);
            #pragma unroll
            for (int u = 0; u < 7; ++u) D[u] += (float)v[u + 1];
            if (cb + 8 < HW) D[7] += (float)Ls[2][cb + 8];
        }
    }

    // ---- group 1 (d2 = +1) ----
    if (gv1) {
        if ((tid >> 3) != 63) {
            const int cb = q0 + 64;
            if (rv[3]) {
                f16x8 v = *(const f16x8*)(&Ls[3][0] + cb);
                #pragma unroll
                for (int u = 1; u < 8; ++u) D[u] += (float)v[u - 1];
                D[0] += (float)Ls[3][cb - 1];
            }
            if (rv[4]) {
                f16x8 v = *(const f16x8*)(&Ls[4][0] + cb);
                #pragma unroll
                for (int u = 0; u < 8; ++u) D[u] += (float)v[u];
            }
            if (rv[5]) {
                f16x8 v = *(const f16x8*)(&Ls[5][0] + cb);
                #pragma unroll
                for (int u = 0; u < 7; ++u) D[u] += (float)v[u + 1];
                if (cb + 8 < HW) D[7] += (float)Ls[5][cb + 8];
            }
        } else {
            #pragma unroll
            for (int u = 0; u < 8; ++u) {
                int q = q0 + u;
                if (q == 4095) continue;
                int c = (q & 63) + 1;
                float a2 = 0.f;
                if (rv[3]) a2 += (float)Ls[3][c - 1];
                if (rv[4]) a2 += (float)Ls[4][c];
                if (rv[5]) a2 += (float)Ls[5][c + 1];
                D[u] += a2;
            }
        }
    }

    // ---- group 2 (d2 = -1) ----
    if (gv2) {
        if ((tid >> 3) != 0) {
            const int cb = q0 - 64;
            if (rv[6]) {
                f16x8 v = *(const f16x8*)(&Ls[6][0] + cb);
                #pragma unroll
                for (int u = 1; u < 8; ++u) D[u] += (float)v[u - 1];
                if (cb > 0) D[0] += (float)Ls[6][cb - 1];
            }
            if (rv[7]) {
                f16x8 v = *(const f16x8*)(&Ls[7][0] + cb);
                #pragma unroll
                for (int u = 0; u < 8; ++u) D[u] += (float)v[u];
            }
            if (rv[8]) {
                f16x8 v = *(const f16x8*)(&Ls[8][0] + cb);
                #pragma unroll
                for (int u = 0; u < 7; ++u) D[u] += (float)v[u + 1];
                if (cb + 8 < HW) D[7] += (float)Ls[8][cb + 8];
            }
        } else {
            #pragma unroll
            for (int u = 0; u < 8; ++u) {
                int q = q0 + u;
                if (q == 0) continue;
                int c = 4031 + q;
                float a2 = 0.f;
                if (rv[6]) a2 += (float)Ls[6][c - 1];
                if (rv[7]) a2 += (float)Ls[7][c];
                if (rv[8]) a2 += (float)Ls[8][c + 1];
                D[u] += a2;
            }
        }
    }

    float lv[8], sv[8];
    float lmax = -1e30f;
    #pragma unroll
    for (int u = 0; u < 8; ++u) {
        float2 m2 = md[q0 + u];
        float l = 10.f * D[u] * m2.x;
        lv[u] = l;
        sv[u] = m2.y;
        lmax = fmaxf(lmax, l);
    }
    #pragma unroll
    for (int off = 32; off > 0; off >>= 1)
        lmax = fmaxf(lmax, __shfl_xor(lmax, off, 64));
    int wv = tid >> 6;
    if ((tid & 63) == 0) wmax[wv] = lmax;
    __syncthreads();
    float M = wmax[0];
    #pragma unroll
    for (int w = 1; w < 8; ++w) M = fmaxf(M, wmax[w]);

    float ev[8];
    float ssum = 0.f;
    #pragma unroll
    for (int u = 0; u < 8; ++u) {
        ev[u] = expf(lv[u] - M);
        ssum += ev[u];
    }
    #pragma unroll
    for (int off = 32; off > 0; off >>= 1)
        ssum += __shfl_xor(ssum, off, 64);
    if ((tid & 63) == 0) wsum[wv] = ssum;
    __syncthreads();
    float tot = 0.f;
    #pragma unroll
    for (int w = 0; w < 8; ++w) tot += wsum[w];

    float inv = 1.f / tot;
    f16x8 outv;
    #pragma unroll
    for (int u = 0; u < 8; ++u)
        outv[u] = (_Float16)(ev[u] * inv * sv[u]);
    *(f16x8*)(V + (size_t)p * HW + q0) = outv;
}

// ---------------- WNT[n, j] = WN[j][n]  (plain transpose, f16) ----------------
__launch_bounds__(256)
__global__ void wnt_transpose(const _Float16* __restrict__ WN0, _Float16* __restrict__ WNT0) {
    const _Float16* WN = WN0 + (size_t)blockIdx.z * HW * KDIM;
    _Float16* WNT = WNT0 + (size_t)blockIdx.z * HW * HW;
    int bx = blockIdx.x;  // j-tile
    int by = blockIdx.y;  // n-tile
    int n0 = by * 64;
    __shared__ unsigned short tile[64][72];
    for (int c = threadIdx.x; c < 512; c += 256) {
        int l = c >> 3, seg = c & 7;
        int j = bx * 64 + l;
        uint4 v = *(const uint4*)(WN + (size_t)j * KDIM + n0 + seg * 8);
        *(uint4*)&tile[l][seg * 8] = v;
    }
    __syncthreads();
    for (int c = threadIdx.x; c < 512; c += 256) {
        int r = c >> 3, seg = c & 7;
        unsigned short tmp[8];
        #pragma unroll
        for (int u = 0; u < 8; ++u) tmp[u] = tile[seg * 8 + u][r];
        *(uint4*)(WNT + (size_t)(n0 + r) * HW + bx * 64 + seg * 8) = *(uint4*)tmp;
    }
}

// ---------------- fold C2T f16 (KDIM x HW, cols p = y*64+x row-major) into shift output ----------------
__launch_bounds__(256)
__global__ void fold_out_t(const _Float16* __restrict__ C2T0, float* __restrict__ out, int b0) {
    const _Float16* C2T = C2T0 + (size_t)blockIdx.z * HW * HW;
    float* outb = out + (size_t)(b0 + blockIdx.z) * COUT * HW;
    int c = blockIdx.x;
    const _Float16* base = C2T + (size_t)c * 9 * HW;
    #pragma unroll 4
    for (int t = 0; t < 16; ++t) {
        int pix = threadIdx.x + t * 256;   // pix = y*64 + x
        int y = pix >> 6, x = pix & 63;
        float s = 0.f;
        #pragma unroll
        for (int dy = 0; dy < 3; ++dy) {
            int yy = y + 1 - dy;
            if ((unsigned)yy >= 64) continue;
            #pragma unroll
            for (int dx = 0; dx < 3; ++dx) {
                int xx = x + 1 - dx;
                if ((unsigned)xx >= 64) continue;
                s += (float)base[(size_t)(dy * 3 + dx) * HW + yy * 64 + xx];
            }
        }
        outb[(size_t)(CIN + c) * HW + pix] = s * (1.f / 9.f);
    }
}

extern "C" void kernel_launch(void* const* d_in, const int* in_sizes, int n_in,
                              void* d_out, int out_size, void* d_ws, size_t ws_size,
                              hipStream_t stream) {
    const float* x = (const float*)d_in[0];
    const float* mask = (const float*)d_in[1];
    const int* mask_thred = (const int*)d_in[3];
    float* out = (float*)d_out;

    // Fixed round-0 layout (172,032,000 B total), no ws_size branching.
    char* ws = (char*)d_ws;
    _Float16* P   = (_Float16*)(ws);                      // 2 x  9,437,184 B
    _Float16* WN  = (_Float16*)(ws + 18874368);           // 2 x  9,437,184 B
    _Float16* S   = (_Float16*)(ws + 37748736);           // 2 x 33,554,432 B (scores; dead after dconv)
    _Float16* R2  = (_Float16*)(ws + 104857600);          // 2 x 33,554,432 B (V lives here)
    float2*   md  = (float2*)(ws + 171966464);            // 2 x 32,768 B
    // lifetime-disjoint aliases (stream-ordered, per-z stride HW*HW):
    _Float16* V   = R2;                                   // dconv output (disjoint from S)
    _Float16* WNT = S;                                    // written AFTER dconv consumed S
    _Float16* C2T = S + (size_t)KDIM * HW;                // gemm2 output (disjoint from WNT per z)

    copy_passthrough<<<(NB * CIN * HW / 4 + 255) / 256, 256, 0, stream>>>((const float4*)x, (float4*)out);

    for (int pp = 0; pp < 2; ++pp) {
        int b0 = pp * 2;
        build_patches_f16<<<dim3((HW * 144 + 255) / 256, 1, 2), 256, 0, stream>>>(x, P, b0);
        build_winn_f16<<<dim3(HW, 1, 2), 256, 0, stream>>>(x, mask, mask_thred, WN, md, b0);
        // GEMM1: S[i][j] = sum_k P[i][k] WN[j][k], M=N=4096, K=1152 (8-phase 256^2, r4 variant)
        gemm1_8ph<<<dim3(256, 1, 2), 512, 131072, stream>>>(P, WN, S);
        dconv_softmax<<<dim3(HW, 1, 2), 512, 0, stream>>>(S, md, V);          // S -> V, LDS-staged
        wnt_transpose<<<dim3(64, KDIM / 64, 2), 256, 0, stream>>>(WN, WNT);   // S dead -> reuse region
        // GEMM2: C2T[n][p] = sum_q WNT[n][q] V[p][q], M=1152, N=4096, K=4096 (128x64 tile, 4.5 blk/CU)
        gemm2_f16_nt<<<dim3(64, KDIM / 128, 2), 256, 0, stream>>>(WNT, V, C2T, HW, HW);
        fold_out_t<<<dim3(CH, 1, 2), 256, 0, stream>>>(C2T, out, b0);
    }
}

// Round 12
// 771.339 us; speedup vs baseline: 1.0646x; 1.0646x over previous
//
#include <hip/hip_runtime.h>
#include <math.h>

#define H 64
#define W 64
#define HW 4096
#define CH 128
#define CIN 256
#define COUT 384
#define KDIM 1152
#define NB 4

typedef _Float16 f16x8 __attribute__((ext_vector_type(8)));
typedef float f32x4 __attribute__((ext_vector_type(4)));

__device__ __forceinline__ void gl_lds16(const _Float16* g, _Float16* l) {
    __builtin_amdgcn_global_load_lds(
        (const __attribute__((address_space(1))) unsigned int*)(g),
        (__attribute__((address_space(3))) unsigned int*)(l), 16, 0, 0);
}

// ---------------- copy former+latter passthrough (float4) ----------------
__global__ void copy_passthrough(const float4* __restrict__ x, float4* __restrict__ out) {
    int idx = blockIdx.x * blockDim.x + threadIdx.x; // over NB*CIN*HW/4
    if (idx >= NB * CIN * HW / 4) return;
    int b = idx / (CIN * HW / 4);
    int rem = idx - b * (CIN * HW / 4);
    out[(size_t)b * (COUT * HW / 4) + rem] = x[idx];
}

// ---------------- im2col of former -> P (HW x KDIM, f16), z = sample in pair ----------------
// v2 mapping: slot-major (slot = idx8>>12, i = idx8&4095). Consecutive lanes share (c,dy,dx)
// and span consecutive ix -> all 8 former-loads are wave-coalesced (were 64-way scattered at
// 16KB channel stride). Write becomes 64-way scattered 16B (1 store) -> ~7x fewer mem requests.
// Same bijection over idx8, identical per-thread math -> bit-identical P.
__global__ void build_patches_f16(const float* __restrict__ x, _Float16* __restrict__ P, int b0) {
    int idx8 = blockIdx.x * blockDim.x + threadIdx.x; // over HW*144
    if (idx8 >= HW * 144) return;
    const float* former = x + (size_t)(b0 + blockIdx.z) * CIN * HW;
    _Float16* Pz = P + (size_t)blockIdx.z * HW * KDIM;
    int slot = idx8 >> 12;          // 0..143  (HW = 4096 = 2^12)
    int i = idx8 & 4095;            // pixel index
    int k0 = slot * 8;
    int iy = i >> 6, ix = i & 63;
    f16x8 v8;
    #pragma unroll
    for (int u = 0; u < 8; ++u) {
        int k = k0 + u;
        int c = k / 9, q = k - c * 9;     // wave-uniform (k uniform across lanes)
        int dy = q / 3, dx = q - dy * 3;
        int y = iy + dy - 1, xx = ix + dx - 1;
        float v = 0.f;
        if ((unsigned)y < H && (unsigned)xx < W) v = former[c * HW + y * W + xx];
        v8[u] = (_Float16)v;
    }
    *(f16x8*)(Pz + (size_t)i * KDIM + k0) = v8;
}

// ---------------- normalized latter windows -> WN (f16), md = {mm, mm*den} ----------------
// v2 reduction: 64-lane shfl_xor wave reduce + 4-slot LDS combine (1 barrier, was 8-barrier tree).
__global__ void build_winn_f16(const float* __restrict__ x, const float* __restrict__ mask,
                               const int* __restrict__ mask_thred_p,
                               _Float16* __restrict__ WN, float2* __restrict__ md, int b0) {
    int b = b0 + blockIdx.z;
    const float* latter = x + (size_t)b * CIN * HW + (size_t)CH * HW;
    const float* maskb = mask + (size_t)b * HW;
    _Float16* WNz = WN + (size_t)blockIdx.z * HW * KDIM;
    float2* mdz = md + (size_t)blockIdx.z * HW;
    int j = blockIdx.x;               // patch index (row-major)
    int y0 = j >> 6, x0 = j & 63;
    __shared__ float red4[4];
    float vals[8];
    float ss = 0.f;
    int k0 = threadIdx.x * 8;
    bool act = (threadIdx.x < 144);
    if (act) {
        #pragma unroll
        for (int u = 0; u < 8; ++u) {
            int k = k0 + u;
            int c = k / 9, q = k - c * 9;
            int dy = q / 3, dx = q - dy * 3;
            int y = y0 + dy - 1, xx = x0 + dx - 1;
            float v = 0.f;
            if ((unsigned)y < H && (unsigned)xx < W) v = latter[c * HW + y * W + xx];
            vals[u] = v;
            ss += v * v;
        }
    }
    #pragma unroll
    for (int off = 32; off > 0; off >>= 1)
        ss += __shfl_xor(ss, off, 64);
    int wv = threadIdx.x >> 6;
    if ((threadIdx.x & 63) == 0) red4[wv] = ss;
    __syncthreads();
    float tot = red4[0] + red4[1] + red4[2] + red4[3];
    float d = fmaxf(sqrtf(tot), 1e-4f);
    float inv = 1.f / d;
    if (act) {
        f16x8 w8;
        #pragma unroll
        for (int u = 0; u < 8; ++u) w8[u] = (_Float16)(vals[u] * inv);
        *(f16x8*)(WNz + (size_t)j * KDIM + k0) = w8;
    }
    if (threadIdx.x == 0) {
        float s = 0.f;
        for (int q = 0; q < 9; ++q) {
            int dy = q / 3, dx = q - dy * 3;
            int y = y0 + dy - 1, xx = x0 + dx - 1;
            if ((unsigned)y < H && (unsigned)xx < W) s += maskb[y * W + xx];
        }
        float mmean = s / 9.f;
        float thr = (float)mask_thred_p[0] / 9.f;
        float m = (mmean <= thr) ? 1.f : 0.f;
        mdz[j] = make_float2(m, m * d);
    }
}

// ---------------- GEMM1: 256x256 tile, BK=64, 8-phase counted-vmcnt (r4-measured-best variant) ----------------
__launch_bounds__(512, 2)
__global__ void gemm1_8ph(const _Float16* __restrict__ A0, const _Float16* __restrict__ B0,
                          _Float16* __restrict__ C0) {
    const int K = KDIM;
    const int NT = KDIM / 64;     // 18 K-tiles
    const _Float16* A = A0 + (size_t)blockIdx.z * HW * KDIM;
    const _Float16* B = B0 + (size_t)blockIdx.z * HW * KDIM;
    _Float16* C = C0 + (size_t)blockIdx.z * HW * HW;

    extern __shared__ _Float16 lds[];
    _Float16* As = lds;            // [2][2][128][64]
    _Float16* Bs = lds + 32768;    // [2][2][128][64]

    int tid = threadIdx.x;
    int wave = tid >> 6, lane = tid & 63;
    int quad = lane >> 4, lr = lane & 15;
    int wr = wave >> 2, wc = wave & 3;

    int lin = blockIdx.x;
    int wg = (lin & 7) * 32 + (lin >> 3);
    int i0 = (wg >> 4) * 256, j0 = (wg & 15) * 256;

    const _Float16* Ab = A + (size_t)i0 * K;
    const _Float16* Bb = B + (size_t)j0 * K;

    f32x4 acc[8][4];
    #pragma unroll
    for (int f = 0; f < 8; ++f)
        #pragma unroll
        for (int g = 0; g < 4; ++g) acc[f][g] = (f32x4){0.f, 0.f, 0.f, 0.f};

    auto stageA = [&](int d, int h, int v) {
        const _Float16* g = Ab + (size_t)(h * 128) * K + v * 64;
        _Float16* dst = As + d * 16384 + h * 8192;
        #pragma unroll
        for (int l = 0; l < 2; ++l) {
            int slot = tid + l * 512;
            int row = slot >> 3;
            gl_lds16(g + (size_t)row * K + (((slot & 7) ^ (row & 7)) << 3), dst + slot * 8);
        }
    };
    auto stageB = [&](int d, int h, int v) {
        const _Float16* g = Bb + (size_t)(h * 128) * K + v * 64;
        _Float16* dst = Bs + d * 16384 + h * 8192;
        #pragma unroll
        for (int l = 0; l < 2; ++l) {
            int slot = tid + l * 512;
            int row = slot >> 3;
            gl_lds16(g + (size_t)row * K + (((slot & 7) ^ (row & 7)) << 3), dst + slot * 8);
        }
    };

    stageA(0, 0, 0); stageB(0, 1, 0); stageA(0, 1, 0); stageB(0, 0, 0);
    stageA(1, 0, 1); stageB(1, 1, 1);
    asm volatile("s_waitcnt vmcnt(4)" ::: "memory");
    __builtin_amdgcn_s_barrier();
    __builtin_amdgcn_sched_barrier(0);

    for (int u = 0; u < NT; ++u) {
        int d = u & 1;
        #pragma unroll
        for (int ph = 0; ph < 4; ++ph) {
            const int mh = ph >> 1;
            const int nh = (ph == 1 || ph == 2) ? 1 : 0;
            const _Float16* Ah = As + d * 16384 + mh * 8192;
            const _Float16* Bh = Bs + d * 16384 + nh * 8192;
            f16x8 af[4][2], bfr[2][2];
            #pragma unroll
            for (int f = 0; f < 4; ++f)
                #pragma unroll
                for (int ks = 0; ks < 2; ++ks)
                    af[f][ks] = *(const f16x8*)(Ah + (wr * 16 + f * 32 + lr) * 64 +
                                                ((((ks << 2) | quad) ^ (lr & 7)) << 3));
            #pragma unroll
            for (int g = 0; g < 2; ++g)
                #pragma unroll
                for (int ks = 0; ks < 2; ++ks)
                    bfr[g][ks] = *(const f16x8*)(Bh + (wc * 16 + g * 64 + lr) * 64 +
                                                 ((((ks << 2) | quad) ^ (lr & 7)) << 3));
            if (ph == 0)      { if (u + 1 < NT) stageA(d ^ 1, 1, u + 1); }
            else if (ph == 1) { if (u + 1 < NT) stageB(d ^ 1, 0, u + 1); }
            else if (ph == 2) { if (u + 2 < NT) stageA(d, 0, u + 2); }
            else              { if (u + 2 < NT) stageB(d, 1, u + 2); }

            __builtin_amdgcn_s_barrier();
            __builtin_amdgcn_s_setprio(1);
            #pragma unroll
            for (int f = 0; f < 4; ++f)
                #pragma unroll
                for (int g = 0; g < 2; ++g)
                    #pragma unroll
                    for (int ks = 0; ks < 2; ++ks)
                        acc[mh * 4 + f][nh * 2 + g] = __builtin_amdgcn_mfma_f32_16x16x32_f16(
                            af[f][ks], bfr[g][ks], acc[mh * 4 + f][nh * 2 + g], 0, 0, 0);
            __builtin_amdgcn_s_setprio(0);

            if (ph == 3) {
                if (u + 2 < NT)      asm volatile("s_waitcnt vmcnt(4)" ::: "memory");
                else if (u + 1 < NT) asm volatile("s_waitcnt vmcnt(0)" ::: "memory");
                __builtin_amdgcn_sched_barrier(0);
            }
            __builtin_amdgcn_s_barrier();
        }
    }

    #pragma unroll
    for (int f = 0; f < 8; ++f) {
        #pragma unroll
        for (int r = 0; r < 4; ++r) {
            int row = i0 + wr * 16 + f * 32 + quad * 4 + r;
            _Float16* Cr = C + (size_t)row * HW + j0 + wc * 16 + lr;
            #pragma unroll
            for (int g = 0; g < 4; ++g)
                Cr[g * 64] = (_Float16)acc[f][g][r];
        }
    }
}

// ---------------- GEMM2: MFMA f16 NT, 128(M)x64(N) tile, BK=64, full K, f16 out ----------------
// Measured-best for M=1152: 1152 blocks = 4.5/CU -> cross-block overlap (98.5 us).
// 256^2-8ph (119 us, r5) and 128^2 (107.7 us, r10) both measured worse at this shape.
__launch_bounds__(256)
__global__ void gemm2_f16_nt(const _Float16* __restrict__ A0, const _Float16* __restrict__ B0,
                             _Float16* __restrict__ C0, int K, int ldc) {
    const _Float16* A = A0 + (size_t)blockIdx.z * HW * HW;   // WNT_z
    const _Float16* B = B0 + (size_t)blockIdx.z * HW * HW;   // V_z
    _Float16* C = C0 + (size_t)blockIdx.z * HW * HW;         // C2T_z
    __shared__ _Float16 As[128 * 64];
    __shared__ _Float16 Bs[64 * 64];
    int tid = threadIdx.x;
    int wave = tid >> 6, lane = tid & 63;
    int quad = lane >> 4, lr = lane & 15;
    int wr = wave >> 1, wc = wave & 1;
    int i0 = blockIdx.y * 128, j0 = blockIdx.x * 64;

    int r0 = tid >> 3;
    int lk = ((tid & 7) ^ ((tid >> 3) & 7)) * 8;

    f32x4 acc[4][2];
    #pragma unroll
    for (int a = 0; a < 4; ++a)
        #pragma unroll
        for (int b = 0; b < 2; ++b) acc[a][b] = (f32x4){0.f, 0.f, 0.f, 0.f};

    const _Float16* Ab = A + (size_t)i0 * K;
    const _Float16* Bb = B + (size_t)j0 * K;

    int ra[4][2], rb[2][2];
    #pragma unroll
    for (int t = 0; t < 4; ++t) {
        int rowA = wr * 64 + t * 16 + lr;
        #pragma unroll
        for (int s = 0; s < 2; ++s)
            ra[t][s] = rowA * 64 + (((quad + 4 * s) ^ (lr & 7)) * 8);
    }
    #pragma unroll
    for (int t = 0; t < 2; ++t) {
        int rowB = wc * 32 + t * 16 + lr;
        #pragma unroll
        for (int s = 0; s < 2; ++s)
            rb[t][s] = rowB * 64 + (((quad + 4 * s) ^ (lr & 7)) * 8);
    }

    for (int k0 = 0; k0 < K; k0 += 64) {
        __syncthreads();
        #pragma unroll
        for (int j = 0; j < 4; ++j) {
            int row = r0 + j * 32;
            gl_lds16(Ab + (size_t)row * K + k0 + lk, As + (tid + j * 256) * 8);
        }
        #pragma unroll
        for (int j = 0; j < 2; ++j) {
            int row = r0 + j * 32;
            gl_lds16(Bb + (size_t)row * K + k0 + lk, Bs + (tid + j * 256) * 8);
        }
        __syncthreads();
        #pragma unroll
        for (int s = 0; s < 2; ++s) {
            f16x8 af[4], bfr[2];
            #pragma unroll
            for (int mi = 0; mi < 4; ++mi) af[mi] = *(const f16x8*)(As + ra[mi][s]);
            #pragma unroll
            for (int ni = 0; ni < 2; ++ni) bfr[ni] = *(const f16x8*)(Bs + rb[ni][s]);
            #pragma unroll
            for (int mi = 0; mi < 4; ++mi)
                #pragma unroll
                for (int ni = 0; ni < 2; ++ni)
                    acc[mi][ni] = __builtin_amdgcn_mfma_f32_16x16x32_f16(af[mi], bfr[ni], acc[mi][ni], 0, 0, 0);
        }
    }

    #pragma unroll
    for (int mi = 0; mi < 4; ++mi) {
        #pragma unroll
        for (int r = 0; r < 4; ++r) {
            int row = i0 + wr * 64 + mi * 16 + quad * 4 + r;
            _Float16* Cr = C + (size_t)row * ldc + j0 + wc * 32 + lr;
            #pragma unroll
            for (int ni = 0; ni < 2; ++ni)
                Cr[ni * 16] = (_Float16)acc[mi][ni][r];
        }
    }
}

// ---------------- fused diag-conv^2 + softmax, LDS-staged (r3/r4-measured-best) ----------------
__launch_bounds__(512)
__global__ void dconv_softmax(const _Float16* __restrict__ S0, const float2* __restrict__ md0,
                              _Float16* __restrict__ V0) {
    const _Float16* S = S0 + (size_t)blockIdx.z * HW * HW;
    const float2* md = md0 + (size_t)blockIdx.z * HW;
    _Float16* V = V0 + (size_t)blockIdx.z * HW * HW;
    int p = (blockIdx.x & 7) * 512 + (blockIdx.x >> 3);   // XCD-contiguous p ranges
    int tid = threadIdx.x;
    int q0 = tid * 8;

    __shared__ _Float16 Ls[9][HW];     // 73,728 B -> 2 blocks/CU
    __shared__ float wmax[8], wsum[8];

    const int P1 = ((p >> 6) < 63) ? (p + 64) : ((p & 63) + 1);   // valid iff p != 4095
    const int P0 = ((p >> 6) > 0) ? (p - 64) : (4031 + (p & 63)); // valid iff p != 0
    const bool gv1 = (p != 4095), gv2 = (p != 0);

    int rows[9];
    bool rv[9];
    rows[0] = p - 1;  rows[1] = p;  rows[2] = p + 1;
    rows[3] = P1 - 1; rows[4] = P1; rows[5] = P1 + 1;
    rows[6] = P0 - 1; rows[7] = P0; rows[8] = P0 + 1;
    rv[0] = ((unsigned)(p - 1) < HW);
    rv[1] = true;
    rv[2] = ((unsigned)(p + 1) < HW);
    rv[3] = gv1 && ((unsigned)(P1 - 1) < HW);
    rv[4] = gv1;
    rv[5] = gv1 && ((unsigned)(P1 + 1) < HW);
    rv[6] = gv2 && ((unsigned)(P0 - 1) < HW);
    rv[7] = gv2;
    rv[8] = gv2 && ((unsigned)(P0 + 1) < HW);

    #pragma unroll
    for (int s = 0; s < 9; ++s) {
        if (rv[s])
            gl_lds16(S + (size_t)rows[s] * HW + q0, &Ls[s][0] + q0);
    }
    __syncthreads();   // drains vmcnt before barrier

    float D[8] = {0.f, 0.f, 0.f, 0.f, 0.f, 0.f, 0.f, 0.f};

    // ---- group 0 (d2 = 0): cols q0 + d1 ----
    {
        const int cb = q0;
        if (rv[0]) {
            f16x8 v = *(const f16x8*)(&Ls[0][0] + cb);
            #pragma unroll
            for (int u = 1; u < 8; ++u) D[u] += (float)v[u - 1];
            if (cb > 0) D[0] += (float)Ls[0][cb - 1];
        }
        {
            f16x8 v = *(const f16x8*)(&Ls[1][0] + cb);
            #pragma unroll
            for (int u = 0; u < 8; ++u) D[u] += (float)v[u];
        }
        if (rv[2]) {
            f16x8 v = *(const f16x8*)(&Ls[2][0] + cb);
            #pragma unroll
            for (int u = 0; u < 7; ++u) D[u] += (float)v[u + 1];
            if (cb + 8 < HW) D[7] += (float)Ls[2][cb + 8];
        }
    }

    // ---- group 1 (d2 = +1) ----
    if (gv1) {
        if ((tid >> 3) != 63) {
            const int cb = q0 + 64;
            if (rv[3]) {
                f16x8 v = *(const f16x8*)(&Ls[3][0] + cb);
                #pragma unroll
                for (int u = 1; u < 8; ++u) D[u] += (float)v[u - 1];
                D[0] += (float)Ls[3][cb - 1];
            }
            if (rv[4]) {
                f16x8 v = *(const f16x8*)(&Ls[4][0] + cb);
                #pragma unroll
                for (int u = 0; u < 8; ++u) D[u] += (float)v[u];
            }
            if (rv[5]) {
                f16x8 v = *(const f16x8*)(&Ls[5][0] + cb);
                #pragma unroll
                for (int u = 0; u < 7; ++u) D[u] += (float)v[u + 1];
                if (cb + 8 < HW) D[7] += (float)Ls[5][cb + 8];
            }
        } else {
            #pragma unroll
            for (int u = 0; u < 8; ++u) {
                int q = q0 + u;
                if (q == 4095) continue;
                int c = (q & 63) + 1;
                float a2 = 0.f;
                if (rv[3]) a2 += (float)Ls[3][c - 1];
                if (rv[4]) a2 += (float)Ls[4][c];
                if (rv[5]) a2 += (float)Ls[5][c + 1];
                D[u] += a2;
            }
        }
    }

    // ---- group 2 (d2 = -1) ----
    if (gv2) {
        if ((tid >> 3) != 0) {
            const int cb = q0 - 64;
            if (rv[6]) {
                f16x8 v = *(const f16x8*)(&Ls[6][0] + cb);
                #pragma unroll
                for (int u = 1; u < 8; ++u) D[u] += (float)v[u - 1];
                if (cb > 0) D[0] += (float)Ls[6][cb - 1];
            }
            if (rv[7]) {
                f16x8 v = *(const f16x8*)(&Ls[7][0] + cb);
                #pragma unroll
                for (int u = 0; u < 8; ++u) D[u] += (float)v[u];
            }
            if (rv[8]) {
                f16x8 v = *(const f16x8*)(&Ls[8][0] + cb);
                #pragma unroll
                for (int u = 0; u < 7; ++u) D[u] += (float)v[u + 1];
                if (cb + 8 < HW) D[7] += (float)Ls[8][cb + 8];
            }
        } else {
            #pragma unroll
            for (int u = 0; u < 8; ++u) {
                int q = q0 + u;
                if (q == 0) continue;
                int c = 4031 + q;
                float a2 = 0.f;
                if (rv[6]) a2 += (float)Ls[6][c - 1];
                if (rv[7]) a2 += (float)Ls[7][c];
                if (rv[8]) a2 += (float)Ls[8][c + 1];
                D[u] += a2;
            }
        }
    }

    float lv[8], sv[8];
    float lmax = -1e30f;
    #pragma unroll
    for (int u = 0; u < 8; ++u) {
        float2 m2 = md[q0 + u];
        float l = 10.f * D[u] * m2.x;
        lv[u] = l;
        sv[u] = m2.y;
        lmax = fmaxf(lmax, l);
    }
    #pragma unroll
    for (int off = 32; off > 0; off >>= 1)
        lmax = fmaxf(lmax, __shfl_xor(lmax, off, 64));
    int wv = tid >> 6;
    if ((tid & 63) == 0) wmax[wv] = lmax;
    __syncthreads();
    float M = wmax[0];
    #pragma unroll
    for (int w = 1; w < 8; ++w) M = fmaxf(M, wmax[w]);

    float ev[8];
    float ssum = 0.f;
    #pragma unroll
    for (int u = 0; u < 8; ++u) {
        ev[u] = expf(lv[u] - M);
        ssum += ev[u];
    }
    #pragma unroll
    for (int off = 32; off > 0; off >>= 1)
        ssum += __shfl_xor(ssum, off, 64);
    if ((tid & 63) == 0) wsum[wv] = ssum;
    __syncthreads();
    float tot = 0.f;
    #pragma unroll
    for (int w = 0; w < 8; ++w) tot += wsum[w];

    float inv = 1.f / tot;
    f16x8 outv;
    #pragma unroll
    for (int u = 0; u < 8; ++u)
        outv[u] = (_Float16)(ev[u] * inv * sv[u]);
    *(f16x8*)(V + (size_t)p * HW + q0) = outv;
}

// ---------------- WNT[n, j] = WN[j][n]  (plain transpose, f16) ----------------
__launch_bounds__(256)
__global__ void wnt_transpose(const _Float16* __restrict__ WN0, _Float16* __restrict__ WNT0) {
    const _Float16* WN = WN0 + (size_t)blockIdx.z * HW * KDIM;
    _Float16* WNT = WNT0 + (size_t)blockIdx.z * HW * HW;
    int bx = blockIdx.x;  // j-tile
    int by = blockIdx.y;  // n-tile
    int n0 = by * 64;
    __shared__ unsigned short tile[64][72];
    for (int c = threadIdx.x; c < 512; c += 256) {
        int l = c >> 3, seg = c & 7;
        int j = bx * 64 + l;
        uint4 v = *(const uint4*)(WN + (size_t)j * KDIM + n0 + seg * 8);
        *(uint4*)&tile[l][seg * 8] = v;
    }
    __syncthreads();
    for (int c = threadIdx.x; c < 512; c += 256) {
        int r = c >> 3, seg = c & 7;
        unsigned short tmp[8];
        #pragma unroll
        for (int u = 0; u < 8; ++u) tmp[u] = tile[seg * 8 + u][r];
        *(uint4*)(WNT + (size_t)(n0 + r) * HW + bx * 64 + seg * 8) = *(uint4*)tmp;
    }
}

// ---------------- fold C2T f16 (KDIM x HW, cols p = y*64+x row-major) into shift output ----------------
__launch_bounds__(256)
__global__ void fold_out_t(const _Float16* __restrict__ C2T0, float* __restrict__ out, int b0) {
    const _Float16* C2T = C2T0 + (size_t)blockIdx.z * HW * HW;
    float* outb = out + (size_t)(b0 + blockIdx.z) * COUT * HW;
    int c = blockIdx.x;
    const _Float16* base = C2T + (size_t)c * 9 * HW;
    #pragma unroll 4
    for (int t = 0; t < 16; ++t) {
        int pix = threadIdx.x + t * 256;   // pix = y*64 + x
        int y = pix >> 6, x = pix & 63;
        float s = 0.f;
        #pragma unroll
        for (int dy = 0; dy < 3; ++dy) {
            int yy = y + 1 - dy;
            if ((unsigned)yy >= 64) continue;
            #pragma unroll
            for (int dx = 0; dx < 3; ++dx) {
                int xx = x + 1 - dx;
                if ((unsigned)xx >= 64) continue;
                s += (float)base[(size_t)(dy * 3 + dx) * HW + yy * 64 + xx];
            }
        }
        outb[(size_t)(CIN + c) * HW + pix] = s * (1.f / 9.f);
    }
}

extern "C" void kernel_launch(void* const* d_in, const int* in_sizes, int n_in,
                              void* d_out, int out_size, void* d_ws, size_t ws_size,
                              hipStream_t stream) {
    const float* x = (const float*)d_in[0];
    const float* mask = (const float*)d_in[1];
    const int* mask_thred = (const int*)d_in[3];
    float* out = (float*)d_out;

    // Fixed round-0 layout (172,032,000 B total), no ws_size branching.
    char* ws = (char*)d_ws;
    _Float16* P   = (_Float16*)(ws);                      // 2 x  9,437,184 B
    _Float16* WN  = (_Float16*)(ws + 18874368);           // 2 x  9,437,184 B
    _Float16* S   = (_Float16*)(ws + 37748736);           // 2 x 33,554,432 B (scores; dead after dconv)
    _Float16* R2  = (_Float16*)(ws + 104857600);          // 2 x 33,554,432 B (V lives here)
    float2*   md  = (float2*)(ws + 171966464);            // 2 x 32,768 B
    // lifetime-disjoint aliases (stream-ordered, per-z stride HW*HW):
    _Float16* V   = R2;                                   // dconv output (disjoint from S)
    _Float16* WNT = S;                                    // written AFTER dconv consumed S
    _Float16* C2T = S + (size_t)KDIM * HW;                // gemm2 output (disjoint from WNT per z)

    copy_passthrough<<<(NB * CIN * HW / 4 + 255) / 256, 256, 0, stream>>>((const float4*)x, (float4*)out);

    for (int pp = 0; pp < 2; ++pp) {
        int b0 = pp * 2;
        build_patches_f16<<<dim3((HW * 144 + 255) / 256, 1, 2), 256, 0, stream>>>(x, P, b0);
        build_winn_f16<<<dim3(HW, 1, 2), 256, 0, stream>>>(x, mask, mask_thred, WN, md, b0);
        // GEMM1: S[i][j] = sum_k P[i][k] WN[j][k], M=N=4096, K=1152 (8-phase 256^2, r4 variant)
        gemm1_8ph<<<dim3(256, 1, 2), 512, 131072, stream>>>(P, WN, S);
        dconv_softmax<<<dim3(HW, 1, 2), 512, 0, stream>>>(S, md, V);          // S -> V, LDS-staged
        wnt_transpose<<<dim3(64, KDIM / 64, 2), 256, 0, stream>>>(WN, WNT);   // S dead -> reuse region
        // GEMM2: C2T[n][p] = sum_q WNT[n][q] V[p][q], M=1152, N=4096, K=4096 (128x64 tile, 4.5 blk/CU)
        gemm2_f16_nt<<<dim3(64, KDIM / 128, 2), 256, 0, stream>>>(WNT, V, C2T, HW, HW);
        fold_out_t<<<dim3(CH, 1, 2), 256, 0, stream>>>(C2T, out, b0);
    }
}

// Round 13
// 723.140 us; speedup vs baseline: 1.1356x; 1.0667x over previous
//
#include <hip/hip_runtime.h>
#include <math.h>

#define H 64
#define W 64
#define HW 4096
#define CH 128
#define CIN 256
#define COUT 384
#define KDIM 1152
#define NB 4

typedef _Float16 f16x8 __attribute__((ext_vector_type(8)));
typedef float f32x4 __attribute__((ext_vector_type(4)));

__device__ __forceinline__ void gl_lds16(const _Float16* g, _Float16* l) {
    __builtin_amdgcn_global_load_lds(
        (const __attribute__((address_space(1))) unsigned int*)(g),
        (__attribute__((address_space(3))) unsigned int*)(l), 16, 0, 0);
}

// ---------------- copy former+latter passthrough (float4) ----------------
__global__ void copy_passthrough(const float4* __restrict__ x, float4* __restrict__ out) {
    int idx = blockIdx.x * blockDim.x + threadIdx.x; // over NB*CIN*HW/4
    if (idx >= NB * CIN * HW / 4) return;
    int b = idx / (CIN * HW / 4);
    int rem = idx - b * (CIN * HW / 4);
    out[(size_t)b * (COUT * HW / 4) + rem] = x[idx];
}

// ---------------- im2col of former -> P (HW x KDIM, f16), z = sample in pair ----------------
// v2 mapping: slot-major (slot = idx8>>12, i = idx8&4095): (c,dy,dx) wave-uniform, ix
// lane-consecutive -> all 8 former-loads wave-coalesced. Bit-identical P (r12-verified).
__global__ void build_patches_f16(const float* __restrict__ x, _Float16* __restrict__ P, int b0) {
    int idx8 = blockIdx.x * blockDim.x + threadIdx.x; // over HW*144
    if (idx8 >= HW * 144) return;
    const float* former = x + (size_t)(b0 + blockIdx.z) * CIN * HW;
    _Float16* Pz = P + (size_t)blockIdx.z * HW * KDIM;
    int slot = idx8 >> 12;          // 0..143  (HW = 4096 = 2^12)
    int i = idx8 & 4095;            // pixel index
    int k0 = slot * 8;
    int iy = i >> 6, ix = i & 63;
    f16x8 v8;
    #pragma unroll
    for (int u = 0; u < 8; ++u) {
        int k = k0 + u;
        int c = k / 9, q = k - c * 9;     // wave-uniform
        int dy = q / 3, dx = q - dy * 3;
        int y = iy + dy - 1, xx = ix + dx - 1;
        float v = 0.f;
        if ((unsigned)y < H && (unsigned)xx < W) v = former[c * HW + y * W + xx];
        v8[u] = (_Float16)v;
    }
    *(f16x8*)(Pz + (size_t)i * KDIM + k0) = v8;
}

// ---------------- normalized latter windows -> WN (f16), md = {mm, mm*den} ----------------
// v2 reduction: 64-lane shfl_xor wave reduce + 4-slot LDS combine (r12-verified).
__global__ void build_winn_f16(const float* __restrict__ x, const float* __restrict__ mask,
                               const int* __restrict__ mask_thred_p,
                               _Float16* __restrict__ WN, float2* __restrict__ md, int b0) {
    int b = b0 + blockIdx.z;
    const float* latter = x + (size_t)b * CIN * HW + (size_t)CH * HW;
    const float* maskb = mask + (size_t)b * HW;
    _Float16* WNz = WN + (size_t)blockIdx.z * HW * KDIM;
    float2* mdz = md + (size_t)blockIdx.z * HW;
    int j = blockIdx.x;               // patch index (row-major)
    int y0 = j >> 6, x0 = j & 63;
    __shared__ float red4[4];
    float vals[8];
    float ss = 0.f;
    int k0 = threadIdx.x * 8;
    bool act = (threadIdx.x < 144);
    if (act) {
        #pragma unroll
        for (int u = 0; u < 8; ++u) {
            int k = k0 + u;
            int c = k / 9, q = k - c * 9;
            int dy = q / 3, dx = q - dy * 3;
            int y = y0 + dy - 1, xx = x0 + dx - 1;
            float v = 0.f;
            if ((unsigned)y < H && (unsigned)xx < W) v = latter[c * HW + y * W + xx];
            vals[u] = v;
            ss += v * v;
        }
    }
    #pragma unroll
    for (int off = 32; off > 0; off >>= 1)
        ss += __shfl_xor(ss, off, 64);
    int wv = threadIdx.x >> 6;
    if ((threadIdx.x & 63) == 0) red4[wv] = ss;
    __syncthreads();
    float tot = red4[0] + red4[1] + red4[2] + red4[3];
    float d = fmaxf(sqrtf(tot), 1e-4f);
    float inv = 1.f / d;
    if (act) {
        f16x8 w8;
        #pragma unroll
        for (int u = 0; u < 8; ++u) w8[u] = (_Float16)(vals[u] * inv);
        *(f16x8*)(WNz + (size_t)j * KDIM + k0) = w8;
    }
    if (threadIdx.x == 0) {
        float s = 0.f;
        for (int q = 0; q < 9; ++q) {
            int dy = q / 3, dx = q - dy * 3;
            int y = y0 + dy - 1, xx = x0 + dx - 1;
            if ((unsigned)y < H && (unsigned)xx < W) s += maskb[y * W + xx];
        }
        float mmean = s / 9.f;
        float thr = (float)mask_thred_p[0] / 9.f;
        float m = (mmean <= thr) ? 1.f : 0.f;
        mdz[j] = make_float2(m, m * d);
    }
}

// ---------------- GEMM1: 256x256 tile, BK=64, 8-phase counted-vmcnt (r4-measured-best variant) ----------------
__launch_bounds__(512, 2)
__global__ void gemm1_8ph(const _Float16* __restrict__ A0, const _Float16* __restrict__ B0,
                          _Float16* __restrict__ C0) {
    const int K = KDIM;
    const int NT = KDIM / 64;     // 18 K-tiles
    const _Float16* A = A0 + (size_t)blockIdx.z * HW * KDIM;
    const _Float16* B = B0 + (size_t)blockIdx.z * HW * KDIM;
    _Float16* C = C0 + (size_t)blockIdx.z * HW * HW;

    extern __shared__ _Float16 lds[];
    _Float16* As = lds;            // [2][2][128][64]
    _Float16* Bs = lds + 32768;    // [2][2][128][64]

    int tid = threadIdx.x;
    int wave = tid >> 6, lane = tid & 63;
    int quad = lane >> 4, lr = lane & 15;
    int wr = wave >> 2, wc = wave & 3;

    int lin = blockIdx.x;
    int wg = (lin & 7) * 32 + (lin >> 3);
    int i0 = (wg >> 4) * 256, j0 = (wg & 15) * 256;

    const _Float16* Ab = A + (size_t)i0 * K;
    const _Float16* Bb = B + (size_t)j0 * K;

    f32x4 acc[8][4];
    #pragma unroll
    for (int f = 0; f < 8; ++f)
        #pragma unroll
        for (int g = 0; g < 4; ++g) acc[f][g] = (f32x4){0.f, 0.f, 0.f, 0.f};

    auto stageA = [&](int d, int h, int v) {
        const _Float16* g = Ab + (size_t)(h * 128) * K + v * 64;
        _Float16* dst = As + d * 16384 + h * 8192;
        #pragma unroll
        for (int l = 0; l < 2; ++l) {
            int slot = tid + l * 512;
            int row = slot >> 3;
            gl_lds16(g + (size_t)row * K + (((slot & 7) ^ (row & 7)) << 3), dst + slot * 8);
        }
    };
    auto stageB = [&](int d, int h, int v) {
        const _Float16* g = Bb + (size_t)(h * 128) * K + v * 64;
        _Float16* dst = Bs + d * 16384 + h * 8192;
        #pragma unroll
        for (int l = 0; l < 2; ++l) {
            int slot = tid + l * 512;
            int row = slot >> 3;
            gl_lds16(g + (size_t)row * K + (((slot & 7) ^ (row & 7)) << 3), dst + slot * 8);
        }
    };

    stageA(0, 0, 0); stageB(0, 1, 0); stageA(0, 1, 0); stageB(0, 0, 0);
    stageA(1, 0, 1); stageB(1, 1, 1);
    asm volatile("s_waitcnt vmcnt(4)" ::: "memory");
    __builtin_amdgcn_s_barrier();
    __builtin_amdgcn_sched_barrier(0);

    for (int u = 0; u < NT; ++u) {
        int d = u & 1;
        #pragma unroll
        for (int ph = 0; ph < 4; ++ph) {
            const int mh = ph >> 1;
            const int nh = (ph == 1 || ph == 2) ? 1 : 0;
            const _Float16* Ah = As + d * 16384 + mh * 8192;
            const _Float16* Bh = Bs + d * 16384 + nh * 8192;
            f16x8 af[4][2], bfr[2][2];
            #pragma unroll
            for (int f = 0; f < 4; ++f)
                #pragma unroll
                for (int ks = 0; ks < 2; ++ks)
                    af[f][ks] = *(const f16x8*)(Ah + (wr * 16 + f * 32 + lr) * 64 +
                                                ((((ks << 2) | quad) ^ (lr & 7)) << 3));
            #pragma unroll
            for (int g = 0; g < 2; ++g)
                #pragma unroll
                for (int ks = 0; ks < 2; ++ks)
                    bfr[g][ks] = *(const f16x8*)(Bh + (wc * 16 + g * 64 + lr) * 64 +
                                                 ((((ks << 2) | quad) ^ (lr & 7)) << 3));
            if (ph == 0)      { if (u + 1 < NT) stageA(d ^ 1, 1, u + 1); }
            else if (ph == 1) { if (u + 1 < NT) stageB(d ^ 1, 0, u + 1); }
            else if (ph == 2) { if (u + 2 < NT) stageA(d, 0, u + 2); }
            else              { if (u + 2 < NT) stageB(d, 1, u + 2); }

            __builtin_amdgcn_s_barrier();
            __builtin_amdgcn_s_setprio(1);
            #pragma unroll
            for (int f = 0; f < 4; ++f)
                #pragma unroll
                for (int g = 0; g < 2; ++g)
                    #pragma unroll
                    for (int ks = 0; ks < 2; ++ks)
                        acc[mh * 4 + f][nh * 2 + g] = __builtin_amdgcn_mfma_f32_16x16x32_f16(
                            af[f][ks], bfr[g][ks], acc[mh * 4 + f][nh * 2 + g], 0, 0, 0);
            __builtin_amdgcn_s_setprio(0);

            if (ph == 3) {
                if (u + 2 < NT)      asm volatile("s_waitcnt vmcnt(4)" ::: "memory");
                else if (u + 1 < NT) asm volatile("s_waitcnt vmcnt(0)" ::: "memory");
                __builtin_amdgcn_sched_barrier(0);
            }
            __builtin_amdgcn_s_barrier();
        }
    }

    #pragma unroll
    for (int f = 0; f < 8; ++f) {
        #pragma unroll
        for (int r = 0; r < 4; ++r) {
            int row = i0 + wr * 16 + f * 32 + quad * 4 + r;
            _Float16* Cr = C + (size_t)row * HW + j0 + wc * 16 + lr;
            #pragma unroll
            for (int g = 0; g < 4; ++g)
                Cr[g * 64] = (_Float16)acc[f][g][r];
        }
    }
}

// ---------------- GEMM2: MFMA f16 NT, 128(M)x64(N) tile, BK=64, full K, f16 out ----------------
// Measured-best for M=1152: 1152 blocks = 4.5/CU -> cross-block overlap (98.5 us).
// 256^2-8ph (119 us, r5) and 128^2 (107.7 us, r10) both measured worse at this shape.
__launch_bounds__(256)
__global__ void gemm2_f16_nt(const _Float16* __restrict__ A0, const _Float16* __restrict__ B0,
                             _Float16* __restrict__ C0, int K, int ldc) {
    const _Float16* A = A0 + (size_t)blockIdx.z * HW * HW;   // WNT_z
    const _Float16* B = B0 + (size_t)blockIdx.z * HW * HW;   // V_z
    _Float16* C = C0 + (size_t)blockIdx.z * HW * HW;         // C2T_z
    __shared__ _Float16 As[128 * 64];
    __shared__ _Float16 Bs[64 * 64];
    int tid = threadIdx.x;
    int wave = tid >> 6, lane = tid & 63;
    int quad = lane >> 4, lr = lane & 15;
    int wr = wave >> 1, wc = wave & 1;
    int i0 = blockIdx.y * 128, j0 = blockIdx.x * 64;

    int r0 = tid >> 3;
    int lk = ((tid & 7) ^ ((tid >> 3) & 7)) * 8;

    f32x4 acc[4][2];
    #pragma unroll
    for (int a = 0; a < 4; ++a)
        #pragma unroll
        for (int b = 0; b < 2; ++b) acc[a][b] = (f32x4){0.f, 0.f, 0.f, 0.f};

    const _Float16* Ab = A + (size_t)i0 * K;
    const _Float16* Bb = B + (size_t)j0 * K;

    int ra[4][2], rb[2][2];
    #pragma unroll
    for (int t = 0; t < 4; ++t) {
        int rowA = wr * 64 + t * 16 + lr;
        #pragma unroll
        for (int s = 0; s < 2; ++s)
            ra[t][s] = rowA * 64 + (((quad + 4 * s) ^ (lr & 7)) * 8);
    }
    #pragma unroll
    for (int t = 0; t < 2; ++t) {
        int rowB = wc * 32 + t * 16 + lr;
        #pragma unroll
        for (int s = 0; s < 2; ++s)
            rb[t][s] = rowB * 64 + (((quad + 4 * s) ^ (lr & 7)) * 8);
    }

    for (int k0 = 0; k0 < K; k0 += 64) {
        __syncthreads();
        #pragma unroll
        for (int j = 0; j < 4; ++j) {
            int row = r0 + j * 32;
            gl_lds16(Ab + (size_t)row * K + k0 + lk, As + (tid + j * 256) * 8);
        }
        #pragma unroll
        for (int j = 0; j < 2; ++j) {
            int row = r0 + j * 32;
            gl_lds16(Bb + (size_t)row * K + k0 + lk, Bs + (tid + j * 256) * 8);
        }
        __syncthreads();
        #pragma unroll
        for (int s = 0; s < 2; ++s) {
            f16x8 af[4], bfr[2];
            #pragma unroll
            for (int mi = 0; mi < 4; ++mi) af[mi] = *(const f16x8*)(As + ra[mi][s]);
            #pragma unroll
            for (int ni = 0; ni < 2; ++ni) bfr[ni] = *(const f16x8*)(Bs + rb[ni][s]);
            #pragma unroll
            for (int mi = 0; mi < 4; ++mi)
                #pragma unroll
                for (int ni = 0; ni < 2; ++ni)
                    acc[mi][ni] = __builtin_amdgcn_mfma_f32_16x16x32_f16(af[mi], bfr[ni], acc[mi][ni], 0, 0, 0);
        }
    }

    #pragma unroll
    for (int mi = 0; mi < 4; ++mi) {
        #pragma unroll
        for (int r = 0; r < 4; ++r) {
            int row = i0 + wr * 64 + mi * 16 + quad * 4 + r;
            _Float16* Cr = C + (size_t)row * ldc + j0 + wc * 32 + lr;
            #pragma unroll
            for (int ni = 0; ni < 2; ++ni)
                Cr[ni * 16] = (_Float16)acc[mi][ni][r];
        }
    }
}

// ---------------- fused diag-conv^2 + softmax, LDS-staged (r3/r4-measured-best) ----------------
__launch_bounds__(512)
__global__ void dconv_softmax(const _Float16* __restrict__ S0, const float2* __restrict__ md0,
                              _Float16* __restrict__ V0) {
    const _Float16* S = S0 + (size_t)blockIdx.z * HW * HW;
    const float2* md = md0 + (size_t)blockIdx.z * HW;
    _Float16* V = V0 + (size_t)blockIdx.z * HW * HW;
    int p = (blockIdx.x & 7) * 512 + (blockIdx.x >> 3);   // XCD-contiguous p ranges
    int tid = threadIdx.x;
    int q0 = tid * 8;

    __shared__ _Float16 Ls[9][HW];     // 73,728 B -> 2 blocks/CU
    __shared__ float wmax[8], wsum[8];

    const int P1 = ((p >> 6) < 63) ? (p + 64) : ((p & 63) + 1);   // valid iff p != 4095
    const int P0 = ((p >> 6) > 0) ? (p - 64) : (4031 + (p & 63)); // valid iff p != 0
    const bool gv1 = (p != 4095), gv2 = (p != 0);

    int rows[9];
    bool rv[9];
    rows[0] = p - 1;  rows[1] = p;  rows[2] = p + 1;
    rows[3] = P1 - 1; rows[4] = P1; rows[5] = P1 + 1;
    rows[6] = P0 - 1; rows[7] = P0; rows[8] = P0 + 1;
    rv[0] = ((unsigned)(p - 1) < HW);
    rv[1] = true;
    rv[2] = ((unsigned)(p + 1) < HW);
    rv[3] = gv1 && ((unsigned)(P1 - 1) < HW);
    rv[4] = gv1;
    rv[5] = gv1 && ((unsigned)(P1 + 1) < HW);
    rv[6] = gv2 && ((unsigned)(P0 - 1) < HW);
    rv[7] = gv2;
    rv[8] = gv2 && ((unsigned)(P0 + 1) < HW);

    #pragma unroll
    for (int s = 0; s < 9; ++s) {
        if (rv[s])
            gl_lds16(S + (size_t)rows[s] * HW + q0, &Ls[s][0] + q0);
    }
    __syncthreads();   // drains vmcnt before barrier

    float D[8] = {0.f, 0.f, 0.f, 0.f, 0.f, 0.f, 0.f, 0.f};

    // ---- group 0 (d2 = 0): cols q0 + d1 ----
    {
        const int cb = q0;
        if (rv[0]) {
            f16x8 v = *(const f16x8*)(&Ls[0][0] + cb);
            #pragma unroll
            for (int u = 1; u < 8; ++u) D[u] += (float)v[u - 1];
            if (cb > 0) D[0] += (float)Ls[0][cb - 1];
        }
        {
            f16x8 v = *(const f16x8*)(&Ls[1][0] + cb);
            #pragma unroll
            for (int u = 0; u < 8; ++u) D[u] += (float)v[u];
        }
        if (rv[2]) {
            f16x8 v = *(const f16x8*)(&Ls[2][0] + cb);
            #pragma unroll
            for (int u = 0; u < 7; ++u) D[u] += (float)v[u + 1];
            if (cb + 8 < HW) D[7] += (float)Ls[2][cb + 8];
        }
    }

    // ---- group 1 (d2 = +1) ----
    if (gv1) {
        if ((tid >> 3) != 63) {
            const int cb = q0 + 64;
            if (rv[3]) {
                f16x8 v = *(const f16x8*)(&Ls[3][0] + cb);
                #pragma unroll
                for (int u = 1; u < 8; ++u) D[u] += (float)v[u - 1];
                D[0] += (float)Ls[3][cb - 1];
            }
            if (rv[4]) {
                f16x8 v = *(const f16x8*)(&Ls[4][0] + cb);
                #pragma unroll
                for (int u = 0; u < 8; ++u) D[u] += (float)v[u];
            }
            if (rv[5]) {
                f16x8 v = *(const f16x8*)(&Ls[5][0] + cb);
                #pragma unroll
                for (int u = 0; u < 7; ++u) D[u] += (float)v[u + 1];
                if (cb + 8 < HW) D[7] += (float)Ls[5][cb + 8];
            }
        } else {
            #pragma unroll
            for (int u = 0; u < 8; ++u) {
                int q = q0 + u;
                if (q == 4095) continue;
                int c = (q & 63) + 1;
                float a2 = 0.f;
                if (rv[3]) a2 += (float)Ls[3][c - 1];
                if (rv[4]) a2 += (float)Ls[4][c];
                if (rv[5]) a2 += (float)Ls[5][c + 1];
                D[u] += a2;
            }
        }
    }

    // ---- group 2 (d2 = -1) ----
    if (gv2) {
        if ((tid >> 3) != 0) {
            const int cb = q0 - 64;
            if (rv[6]) {
                f16x8 v = *(const f16x8*)(&Ls[6][0] + cb);
                #pragma unroll
                for (int u = 1; u < 8; ++u) D[u] += (float)v[u - 1];
                if (cb > 0) D[0] += (float)Ls[6][cb - 1];
            }
            if (rv[7]) {
                f16x8 v = *(const f16x8*)(&Ls[7][0] + cb);
                #pragma unroll
                for (int u = 0; u < 8; ++u) D[u] += (float)v[u];
            }
            if (rv[8]) {
                f16x8 v = *(const f16x8*)(&Ls[8][0] + cb);
                #pragma unroll
                for (int u = 0; u < 7; ++u) D[u] += (float)v[u + 1];
                if (cb + 8 < HW) D[7] += (float)Ls[8][cb + 8];
            }
        } else {
            #pragma unroll
            for (int u = 0; u < 8; ++u) {
                int q = q0 + u;
                if (q == 0) continue;
                int c = 4031 + q;
                float a2 = 0.f;
                if (rv[6]) a2 += (float)Ls[6][c - 1];
                if (rv[7]) a2 += (float)Ls[7][c];
                if (rv[8]) a2 += (float)Ls[8][c + 1];
                D[u] += a2;
            }
        }
    }

    float lv[8], sv[8];
    float lmax = -1e30f;
    #pragma unroll
    for (int u = 0; u < 8; ++u) {
        float2 m2 = md[q0 + u];
        float l = 10.f * D[u] * m2.x;
        lv[u] = l;
        sv[u] = m2.y;
        lmax = fmaxf(lmax, l);
    }
    #pragma unroll
    for (int off = 32; off > 0; off >>= 1)
        lmax = fmaxf(lmax, __shfl_xor(lmax, off, 64));
    int wv = tid >> 6;
    if ((tid & 63) == 0) wmax[wv] = lmax;
    __syncthreads();
    float M = wmax[0];
    #pragma unroll
    for (int w = 1; w < 8; ++w) M = fmaxf(M, wmax[w]);

    float ev[8];
    float ssum = 0.f;
    #pragma unroll
    for (int u = 0; u < 8; ++u) {
        ev[u] = expf(lv[u] - M);
        ssum += ev[u];
    }
    #pragma unroll
    for (int off = 32; off > 0; off >>= 1)
        ssum += __shfl_xor(ssum, off, 64);
    if ((tid & 63) == 0) wsum[wv] = ssum;
    __syncthreads();
    float tot = 0.f;
    #pragma unroll
    for (int w = 0; w < 8; ++w) tot += wsum[w];

    float inv = 1.f / tot;
    f16x8 outv;
    #pragma unroll
    for (int u = 0; u < 8; ++u)
        outv[u] = (_Float16)(ev[u] * inv * sv[u]);
    *(f16x8*)(V + (size_t)p * HW + q0) = outv;
}

// ---------------- WNT[n, j] = WN[j][n]  (plain transpose, f16) ----------------
__launch_bounds__(256)
__global__ void wnt_transpose(const _Float16* __restrict__ WN0, _Float16* __restrict__ WNT0) {
    const _Float16* WN = WN0 + (size_t)blockIdx.z * HW * KDIM;
    _Float16* WNT = WNT0 + (size_t)blockIdx.z * HW * HW;
    int bx = blockIdx.x;  // j-tile
    int by = blockIdx.y;  // n-tile
    int n0 = by * 64;
    __shared__ unsigned short tile[64][72];
    for (int c = threadIdx.x; c < 512; c += 256) {
        int l = c >> 3, seg = c & 7;
        int j = bx * 64 + l;
        uint4 v = *(const uint4*)(WN + (size_t)j * KDIM + n0 + seg * 8);
        *(uint4*)&tile[l][seg * 8] = v;
    }
    __syncthreads();
    for (int c = threadIdx.x; c < 512; c += 256) {
        int r = c >> 3, seg = c & 7;
        unsigned short tmp[8];
        #pragma unroll
        for (int u = 0; u < 8; ++u) tmp[u] = tile[seg * 8 + u][r];
        *(uint4*)(WNT + (size_t)(n0 + r) * HW + bx * 64 + seg * 8) = *(uint4*)tmp;
    }
}

// ---------------- fold C2T f16 (KDIM x HW) into shift output, v2: 8-pixel vectorized ----------------
// Each thread: one 8-pixel x-segment (seg = by*256 + tid, pix0 = seg*8; x-shifts stay in-row
// since 64 % 8 == 0). Per (dy,dx) plane: aligned f16x8 + one scalar edge (zrow8 pattern).
// FP add order per output preserved (dy-major, dx-minor, one add per plane) -> bit-identical.
// Grid (CH, 2, z) = 512 blocks/dispatch (was 256), ~1/8 the load instructions.
__launch_bounds__(256)
__global__ void fold_out_t(const _Float16* __restrict__ C2T0, float* __restrict__ out, int b0) {
    const _Float16* C2T = C2T0 + (size_t)blockIdx.z * HW * HW;
    float* outb = out + (size_t)(b0 + blockIdx.z) * COUT * HW;
    int c = blockIdx.x;
    const _Float16* base = C2T + (size_t)c * 9 * HW;
    int seg = blockIdx.y * 256 + threadIdx.x;   // 0..511 over HW/8 segments
    int pix0 = seg * 8;                          // multiple of 8
    int y = pix0 >> 6, x0 = pix0 & 63;           // x0 in {0,8,...,56}
    float s[8] = {0.f, 0.f, 0.f, 0.f, 0.f, 0.f, 0.f, 0.f};
    #pragma unroll
    for (int dy = 0; dy < 3; ++dy) {
        int yy = y + 1 - dy;
        if ((unsigned)yy >= 64) continue;
        #pragma unroll
        for (int dx = 0; dx < 3; ++dx) {
            const _Float16* row = base + (size_t)(dy * 3 + dx) * HW + yy * 64;
            f16x8 v = *(const f16x8*)(row + x0);
            if (dx == 1) {               // shift 0
                #pragma unroll
                for (int u = 0; u < 8; ++u) s[u] += (float)v[u];
            } else if (dx == 0) {        // xx = x+1: cols x0+1..x0+8
                #pragma unroll
                for (int u = 0; u < 7; ++u) s[u] += (float)v[u + 1];
                if (x0 + 8 < 64) s[7] += (float)row[x0 + 8];
            } else {                     // dx == 2, xx = x-1: cols x0-1..x0+6
                #pragma unroll
                for (int u = 1; u < 8; ++u) s[u] += (float)v[u - 1];
                if (x0 > 0) s[0] += (float)row[x0 - 1];
            }
        }
    }
    float* op = outb + (size_t)(CIN + c) * HW + pix0;
    f32x4 o0 = {s[0] * (1.f / 9.f), s[1] * (1.f / 9.f), s[2] * (1.f / 9.f), s[3] * (1.f / 9.f)};
    f32x4 o1 = {s[4] * (1.f / 9.f), s[5] * (1.f / 9.f), s[6] * (1.f / 9.f), s[7] * (1.f / 9.f)};
    *(f32x4*)(op) = o0;
    *(f32x4*)(op + 4) = o1;
}

extern "C" void kernel_launch(void* const* d_in, const int* in_sizes, int n_in,
                              void* d_out, int out_size, void* d_ws, size_t ws_size,
                              hipStream_t stream) {
    const float* x = (const float*)d_in[0];
    const float* mask = (const float*)d_in[1];
    const int* mask_thred = (const int*)d_in[3];
    float* out = (float*)d_out;

    // Fixed round-0 layout (172,032,000 B total), no ws_size branching.
    char* ws = (char*)d_ws;
    _Float16* P   = (_Float16*)(ws);                      // 2 x  9,437,184 B
    _Float16* WN  = (_Float16*)(ws + 18874368);           // 2 x  9,437,184 B
    _Float16* S   = (_Float16*)(ws + 37748736);           // 2 x 33,554,432 B (scores; dead after dconv)
    _Float16* R2  = (_Float16*)(ws + 104857600);          // 2 x 33,554,432 B (V lives here)
    float2*   md  = (float2*)(ws + 171966464);            // 2 x 32,768 B
    // lifetime-disjoint aliases (stream-ordered, per-z stride HW*HW):
    _Float16* V   = R2;                                   // dconv output (disjoint from S)
    _Float16* WNT = S;                                    // written AFTER dconv consumed S
    _Float16* C2T = S + (size_t)KDIM * HW;                // gemm2 output (disjoint from WNT per z)

    copy_passthrough<<<(NB * CIN * HW / 4 + 255) / 256, 256, 0, stream>>>((const float4*)x, (float4*)out);

    for (int pp = 0; pp < 2; ++pp) {
        int b0 = pp * 2;
        build_patches_f16<<<dim3((HW * 144 + 255) / 256, 1, 2), 256, 0, stream>>>(x, P, b0);
        build_winn_f16<<<dim3(HW, 1, 2), 256, 0, stream>>>(x, mask, mask_thred, WN, md, b0);
        // GEMM1: S[i][j] = sum_k P[i][k] WN[j][k], M=N=4096, K=1152 (8-phase 256^2, r4 variant)
        gemm1_8ph<<<dim3(256, 1, 2), 512, 131072, stream>>>(P, WN, S);
        dconv_softmax<<<dim3(HW, 1, 2), 512, 0, stream>>>(S, md, V);          // S -> V, LDS-staged
        wnt_transpose<<<dim3(64, KDIM / 64, 2), 256, 0, stream>>>(WN, WNT);   // S dead -> reuse region
        // GEMM2: C2T[n][p] = sum_q WNT[n][q] V[p][q], M=1152, N=4096, K=4096 (128x64 tile, 4.5 blk/CU)
        gemm2_f16_nt<<<dim3(64, KDIM / 128, 2), 256, 0, stream>>>(WNT, V, C2T, HW, HW);
        fold_out_t<<<dim3(CH, 2, 2), 256, 0, stream>>>(C2T, out, b0);
    }
}

// Round 14
// 704.637 us; speedup vs baseline: 1.1654x; 1.0263x over previous
//
#include <hip/hip_runtime.h>
#include <math.h>

#define H 64
#define W 64
#define HW 4096
#define CH 128
#define CIN 256
#define COUT 384
#define KDIM 1152
#define NB 4

typedef _Float16 f16x8 __attribute__((ext_vector_type(8)));
typedef float f32x4 __attribute__((ext_vector_type(4)));

__device__ __forceinline__ void gl_lds16(const _Float16* g, _Float16* l) {
    __builtin_amdgcn_global_load_lds(
        (const __attribute__((address_space(1))) unsigned int*)(g),
        (__attribute__((address_space(3))) unsigned int*)(l), 16, 0, 0);
}

// ---------------- fused prep: copy passthrough + im2col(P) + winn(WN,md), partitioned grid ----------------
// Block ranges (x): [0,copyN) copy; [copyN,copyN+2304) patches; [copyN+2304, +4096) winn.
// All bodies byte-identical to r13's verified kernels -> bit-identical outputs.
__global__ void prep_fused(const float* __restrict__ x, const float* __restrict__ mask,
                           const int* __restrict__ mask_thred_p,
                           _Float16* __restrict__ P, _Float16* __restrict__ WN,
                           float2* __restrict__ md, float4* __restrict__ outv4,
                           int b0, int copyN) {
    __shared__ float red4[4];
    int id = blockIdx.x;
    int z = blockIdx.z;

    if (id < copyN) {
        // ---- copy former+latter passthrough (float4); ids split across z ----
        int idx = (id + z * copyN) * 256 + threadIdx.x;   // covers NB*CIN*HW/4 exactly (copyN=2048)
        if (idx < NB * CIN * HW / 4) {
            int b = idx / (CIN * HW / 4);
            int rem = idx - b * (CIN * HW / 4);
            outv4[(size_t)b * (COUT * HW / 4) + rem] = ((const float4*)x)[idx];
        }
        return;
    }
    id -= copyN;

    if (id < 2304) {
        // ---- im2col of former -> P (slot-major mapping, r12-verified bit-identical) ----
        int idx8 = id * 256 + threadIdx.x;                // < HW*144 = 589824 = 2304*256
        const float* former = x + (size_t)(b0 + z) * CIN * HW;
        _Float16* Pz = P + (size_t)z * HW * KDIM;
        int slot = idx8 >> 12;          // 0..143
        int i = idx8 & 4095;
        int k0 = slot * 8;
        int iy = i >> 6, ix = i & 63;
        f16x8 v8;
        #pragma unroll
        for (int u = 0; u < 8; ++u) {
            int k = k0 + u;
            int c = k / 9, q = k - c * 9;     // wave-uniform
            int dy = q / 3, dx = q - dy * 3;
            int y = iy + dy - 1, xx = ix + dx - 1;
            float v = 0.f;
            if ((unsigned)y < H && (unsigned)xx < W) v = former[c * HW + y * W + xx];
            v8[u] = (_Float16)v;
        }
        *(f16x8*)(Pz + (size_t)i * KDIM + k0) = v8;
        return;
    }
    int j = id - 2304;                                    // 0..4095

    // ---- normalized latter windows -> WN, md (shfl reduce, r12-verified) ----
    int b = b0 + z;
    const float* latter = x + (size_t)b * CIN * HW + (size_t)CH * HW;
    const float* maskb = mask + (size_t)b * HW;
    _Float16* WNz = WN + (size_t)z * HW * KDIM;
    float2* mdz = md + (size_t)z * HW;
    int y0 = j >> 6, x0 = j & 63;
    float vals[8];
    float ss = 0.f;
    int k0 = threadIdx.x * 8;
    bool act = (threadIdx.x < 144);
    if (act) {
        #pragma unroll
        for (int u = 0; u < 8; ++u) {
            int k = k0 + u;
            int c = k / 9, q = k - c * 9;
            int dy = q / 3, dx = q - dy * 3;
            int y = y0 + dy - 1, xx = x0 + dx - 1;
            float v = 0.f;
            if ((unsigned)y < H && (unsigned)xx < W) v = latter[c * HW + y * W + xx];
            vals[u] = v;
            ss += v * v;
        }
    }
    #pragma unroll
    for (int off = 32; off > 0; off >>= 1)
        ss += __shfl_xor(ss, off, 64);
    int wv = threadIdx.x >> 6;
    if ((threadIdx.x & 63) == 0) red4[wv] = ss;
    __syncthreads();
    float tot = red4[0] + red4[1] + red4[2] + red4[3];
    float d = fmaxf(sqrtf(tot), 1e-4f);
    float inv = 1.f / d;
    if (act) {
        f16x8 w8;
        #pragma unroll
        for (int u = 0; u < 8; ++u) w8[u] = (_Float16)(vals[u] * inv);
        *(f16x8*)(WNz + (size_t)j * KDIM + k0) = w8;
    }
    if (threadIdx.x == 0) {
        float s = 0.f;
        for (int q = 0; q < 9; ++q) {
            int dy = q / 3, dx = q - dy * 3;
            int y = y0 + dy - 1, xx = x0 + dx - 1;
            if ((unsigned)y < H && (unsigned)xx < W) s += maskb[y * W + xx];
        }
        float mmean = s / 9.f;
        float thr = (float)mask_thred_p[0] / 9.f;
        float m = (mmean <= thr) ? 1.f : 0.f;
        mdz[j] = make_float2(m, m * d);
    }
}

// ---------------- GEMM1: 256x256 tile, BK=64, 8-phase counted-vmcnt (r4-measured-best variant) ----------------
__launch_bounds__(512, 2)
__global__ void gemm1_8ph(const _Float16* __restrict__ A0, const _Float16* __restrict__ B0,
                          _Float16* __restrict__ C0) {
    const int K = KDIM;
    const int NT = KDIM / 64;     // 18 K-tiles
    const _Float16* A = A0 + (size_t)blockIdx.z * HW * KDIM;
    const _Float16* B = B0 + (size_t)blockIdx.z * HW * KDIM;
    _Float16* C = C0 + (size_t)blockIdx.z * HW * HW;

    extern __shared__ _Float16 lds[];
    _Float16* As = lds;            // [2][2][128][64]
    _Float16* Bs = lds + 32768;    // [2][2][128][64]

    int tid = threadIdx.x;
    int wave = tid >> 6, lane = tid & 63;
    int quad = lane >> 4, lr = lane & 15;
    int wr = wave >> 2, wc = wave & 3;

    int lin = blockIdx.x;
    int wg = (lin & 7) * 32 + (lin >> 3);
    int i0 = (wg >> 4) * 256, j0 = (wg & 15) * 256;

    const _Float16* Ab = A + (size_t)i0 * K;
    const _Float16* Bb = B + (size_t)j0 * K;

    f32x4 acc[8][4];
    #pragma unroll
    for (int f = 0; f < 8; ++f)
        #pragma unroll
        for (int g = 0; g < 4; ++g) acc[f][g] = (f32x4){0.f, 0.f, 0.f, 0.f};

    auto stageA = [&](int d, int h, int v) {
        const _Float16* g = Ab + (size_t)(h * 128) * K + v * 64;
        _Float16* dst = As + d * 16384 + h * 8192;
        #pragma unroll
        for (int l = 0; l < 2; ++l) {
            int slot = tid + l * 512;
            int row = slot >> 3;
            gl_lds16(g + (size_t)row * K + (((slot & 7) ^ (row & 7)) << 3), dst + slot * 8);
        }
    };
    auto stageB = [&](int d, int h, int v) {
        const _Float16* g = Bb + (size_t)(h * 128) * K + v * 64;
        _Float16* dst = Bs + d * 16384 + h * 8192;
        #pragma unroll
        for (int l = 0; l < 2; ++l) {
            int slot = tid + l * 512;
            int row = slot >> 3;
            gl_lds16(g + (size_t)row * K + (((slot & 7) ^ (row & 7)) << 3), dst + slot * 8);
        }
    };

    stageA(0, 0, 0); stageB(0, 1, 0); stageA(0, 1, 0); stageB(0, 0, 0);
    stageA(1, 0, 1); stageB(1, 1, 1);
    asm volatile("s_waitcnt vmcnt(4)" ::: "memory");
    __builtin_amdgcn_s_barrier();
    __builtin_amdgcn_sched_barrier(0);

    for (int u = 0; u < NT; ++u) {
        int d = u & 1;
        #pragma unroll
        for (int ph = 0; ph < 4; ++ph) {
            const int mh = ph >> 1;
            const int nh = (ph == 1 || ph == 2) ? 1 : 0;
            const _Float16* Ah = As + d * 16384 + mh * 8192;
            const _Float16* Bh = Bs + d * 16384 + nh * 8192;
            f16x8 af[4][2], bfr[2][2];
            #pragma unroll
            for (int f = 0; f < 4; ++f)
                #pragma unroll
                for (int ks = 0; ks < 2; ++ks)
                    af[f][ks] = *(const f16x8*)(Ah + (wr * 16 + f * 32 + lr) * 64 +
                                                ((((ks << 2) | quad) ^ (lr & 7)) << 3));
            #pragma unroll
            for (int g = 0; g < 2; ++g)
                #pragma unroll
                for (int ks = 0; ks < 2; ++ks)
                    bfr[g][ks] = *(const f16x8*)(Bh + (wc * 16 + g * 64 + lr) * 64 +
                                                 ((((ks << 2) | quad) ^ (lr & 7)) << 3));
            if (ph == 0)      { if (u + 1 < NT) stageA(d ^ 1, 1, u + 1); }
            else if (ph == 1) { if (u + 1 < NT) stageB(d ^ 1, 0, u + 1); }
            else if (ph == 2) { if (u + 2 < NT) stageA(d, 0, u + 2); }
            else              { if (u + 2 < NT) stageB(d, 1, u + 2); }

            __builtin_amdgcn_s_barrier();
            __builtin_amdgcn_s_setprio(1);
            #pragma unroll
            for (int f = 0; f < 4; ++f)
                #pragma unroll
                for (int g = 0; g < 2; ++g)
                    #pragma unroll
                    for (int ks = 0; ks < 2; ++ks)
                        acc[mh * 4 + f][nh * 2 + g] = __builtin_amdgcn_mfma_f32_16x16x32_f16(
                            af[f][ks], bfr[g][ks], acc[mh * 4 + f][nh * 2 + g], 0, 0, 0);
            __builtin_amdgcn_s_setprio(0);

            if (ph == 3) {
                if (u + 2 < NT)      asm volatile("s_waitcnt vmcnt(4)" ::: "memory");
                else if (u + 1 < NT) asm volatile("s_waitcnt vmcnt(0)" ::: "memory");
                __builtin_amdgcn_sched_barrier(0);
            }
            __builtin_amdgcn_s_barrier();
        }
    }

    #pragma unroll
    for (int f = 0; f < 8; ++f) {
        #pragma unroll
        for (int r = 0; r < 4; ++r) {
            int row = i0 + wr * 16 + f * 32 + quad * 4 + r;
            _Float16* Cr = C + (size_t)row * HW + j0 + wc * 16 + lr;
            #pragma unroll
            for (int g = 0; g < 4; ++g)
                Cr[g * 64] = (_Float16)acc[f][g][r];
        }
    }
}

// ---------------- GEMM2: MFMA f16 NT, 128(M)x64(N) tile, BK=64, full K, f16 out ----------------
// Measured-best for M=1152: 1152 blocks = 4.5/CU -> cross-block overlap (98.5 us).
__launch_bounds__(256)
__global__ void gemm2_f16_nt(const _Float16* __restrict__ A0, const _Float16* __restrict__ B0,
                             _Float16* __restrict__ C0, int K, int ldc) {
    const _Float16* A = A0 + (size_t)blockIdx.z * HW * HW;   // WNT_z
    const _Float16* B = B0 + (size_t)blockIdx.z * HW * HW;   // V_z
    _Float16* C = C0 + (size_t)blockIdx.z * HW * HW;         // C2T_z
    __shared__ _Float16 As[128 * 64];
    __shared__ _Float16 Bs[64 * 64];
    int tid = threadIdx.x;
    int wave = tid >> 6, lane = tid & 63;
    int quad = lane >> 4, lr = lane & 15;
    int wr = wave >> 1, wc = wave & 1;
    int i0 = blockIdx.y * 128, j0 = blockIdx.x * 64;

    int r0 = tid >> 3;
    int lk = ((tid & 7) ^ ((tid >> 3) & 7)) * 8;

    f32x4 acc[4][2];
    #pragma unroll
    for (int a = 0; a < 4; ++a)
        #pragma unroll
        for (int b = 0; b < 2; ++b) acc[a][b] = (f32x4){0.f, 0.f, 0.f, 0.f};

    const _Float16* Ab = A + (size_t)i0 * K;
    const _Float16* Bb = B + (size_t)j0 * K;

    int ra[4][2], rb[2][2];
    #pragma unroll
    for (int t = 0; t < 4; ++t) {
        int rowA = wr * 64 + t * 16 + lr;
        #pragma unroll
        for (int s = 0; s < 2; ++s)
            ra[t][s] = rowA * 64 + (((quad + 4 * s) ^ (lr & 7)) * 8);
    }
    #pragma unroll
    for (int t = 0; t < 2; ++t) {
        int rowB = wc * 32 + t * 16 + lr;
        #pragma unroll
        for (int s = 0; s < 2; ++s)
            rb[t][s] = rowB * 64 + (((quad + 4 * s) ^ (lr & 7)) * 8);
    }

    for (int k0 = 0; k0 < K; k0 += 64) {
        __syncthreads();
        #pragma unroll
        for (int j = 0; j < 4; ++j) {
            int row = r0 + j * 32;
            gl_lds16(Ab + (size_t)row * K + k0 + lk, As + (tid + j * 256) * 8);
        }
        #pragma unroll
        for (int j = 0; j < 2; ++j) {
            int row = r0 + j * 32;
            gl_lds16(Bb + (size_t)row * K + k0 + lk, Bs + (tid + j * 256) * 8);
        }
        __syncthreads();
        #pragma unroll
        for (int s = 0; s < 2; ++s) {
            f16x8 af[4], bfr[2];
            #pragma unroll
            for (int mi = 0; mi < 4; ++mi) af[mi] = *(const f16x8*)(As + ra[mi][s]);
            #pragma unroll
            for (int ni = 0; ni < 2; ++ni) bfr[ni] = *(const f16x8*)(Bs + rb[ni][s]);
            #pragma unroll
            for (int mi = 0; mi < 4; ++mi)
                #pragma unroll
                for (int ni = 0; ni < 2; ++ni)
                    acc[mi][ni] = __builtin_amdgcn_mfma_f32_16x16x32_f16(af[mi], bfr[ni], acc[mi][ni], 0, 0, 0);
        }
    }

    #pragma unroll
    for (int mi = 0; mi < 4; ++mi) {
        #pragma unroll
        for (int r = 0; r < 4; ++r) {
            int row = i0 + wr * 64 + mi * 16 + quad * 4 + r;
            _Float16* Cr = C + (size_t)row * ldc + j0 + wc * 32 + lr;
            #pragma unroll
            for (int ni = 0; ni < 2; ++ni)
                Cr[ni * 16] = (_Float16)acc[mi][ni][r];
        }
    }
}

// ---------------- fused diag-conv^2 + softmax, LDS-staged (r3/r4-measured-best) ----------------
__launch_bounds__(512)
__global__ void dconv_softmax(const _Float16* __restrict__ S0, const float2* __restrict__ md0,
                              _Float16* __restrict__ V0) {
    const _Float16* S = S0 + (size_t)blockIdx.z * HW * HW;
    const float2* md = md0 + (size_t)blockIdx.z * HW;
    _Float16* V = V0 + (size_t)blockIdx.z * HW * HW;
    int p = (blockIdx.x & 7) * 512 + (blockIdx.x >> 3);   // XCD-contiguous p ranges
    int tid = threadIdx.x;
    int q0 = tid * 8;

    __shared__ _Float16 Ls[9][HW];     // 73,728 B -> 2 blocks/CU
    __shared__ float wmax[8], wsum[8];

    const int P1 = ((p >> 6) < 63) ? (p + 64) : ((p & 63) + 1);   // valid iff p != 4095
    const int P0 = ((p >> 6) > 0) ? (p - 64) : (4031 + (p & 63)); // valid iff p != 0
    const bool gv1 = (p != 4095), gv2 = (p != 0);

    int rows[9];
    bool rv[9];
    rows[0] = p - 1;  rows[1] = p;  rows[2] = p + 1;
    rows[3] = P1 - 1; rows[4] = P1; rows[5] = P1 + 1;
    rows[6] = P0 - 1; rows[7] = P0; rows[8] = P0 + 1;
    rv[0] = ((unsigned)(p - 1) < HW);
    rv[1] = true;
    rv[2] = ((unsigned)(p + 1) < HW);
    rv[3] = gv1 && ((unsigned)(P1 - 1) < HW);
    rv[4] = gv1;
    rv[5] = gv1 && ((unsigned)(P1 + 1) < HW);
    rv[6] = gv2 && ((unsigned)(P0 - 1) < HW);
    rv[7] = gv2;
    rv[8] = gv2 && ((unsigned)(P0 + 1) < HW);

    #pragma unroll
    for (int s = 0; s < 9; ++s) {
        if (rv[s])
            gl_lds16(S + (size_t)rows[s] * HW + q0, &Ls[s][0] + q0);
    }
    __syncthreads();   // drains vmcnt before barrier

    float D[8] = {0.f, 0.f, 0.f, 0.f, 0.f, 0.f, 0.f, 0.f};

    // ---- group 0 (d2 = 0): cols q0 + d1 ----
    {
        const int cb = q0;
        if (rv[0]) {
            f16x8 v = *(const f16x8*)(&Ls[0][0] + cb);
            #pragma unroll
            for (int u = 1; u < 8; ++u) D[u] += (float)v[u - 1];
            if (cb > 0) D[0] += (float)Ls[0][cb - 1];
        }
        {
            f16x8 v = *(const f16x8*)(&Ls[1][0] + cb);
            #pragma unroll
            for (int u = 0; u < 8; ++u) D[u] += (float)v[u];
        }
        if (rv[2]) {
            f16x8 v = *(const f16x8*)(&Ls[2][0] + cb);
            #pragma unroll
            for (int u = 0; u < 7; ++u) D[u] += (float)v[u + 1];
            if (cb + 8 < HW) D[7] += (float)Ls[2][cb + 8];
        }
    }

    // ---- group 1 (d2 = +1) ----
    if (gv1) {
        if ((tid >> 3) != 63) {
            const int cb = q0 + 64;
            if (rv[3]) {
                f16x8 v = *(const f16x8*)(&Ls[3][0] + cb);
                #pragma unroll
                for (int u = 1; u < 8; ++u) D[u] += (float)v[u - 1];
                D[0] += (float)Ls[3][cb - 1];
            }
            if (rv[4]) {
                f16x8 v = *(const f16x8*)(&Ls[4][0] + cb);
                #pragma unroll
                for (int u = 0; u < 8; ++u) D[u] += (float)v[u];
            }
            if (rv[5]) {
                f16x8 v = *(const f16x8*)(&Ls[5][0] + cb);
                #pragma unroll
                for (int u = 0; u < 7; ++u) D[u] += (float)v[u + 1];
                if (cb + 8 < HW) D[7] += (float)Ls[5][cb + 8];
            }
        } else {
            #pragma unroll
            for (int u = 0; u < 8; ++u) {
                int q = q0 + u;
                if (q == 4095) continue;
                int c = (q & 63) + 1;
                float a2 = 0.f;
                if (rv[3]) a2 += (float)Ls[3][c - 1];
                if (rv[4]) a2 += (float)Ls[4][c];
                if (rv[5]) a2 += (float)Ls[5][c + 1];
                D[u] += a2;
            }
        }
    }

    // ---- group 2 (d2 = -1) ----
    if (gv2) {
        if ((tid >> 3) != 0) {
            const int cb = q0 - 64;
            if (rv[6]) {
                f16x8 v = *(const f16x8*)(&Ls[6][0] + cb);
                #pragma unroll
                for (int u = 1; u < 8; ++u) D[u] += (float)v[u - 1];
                if (cb > 0) D[0] += (float)Ls[6][cb - 1];
            }
            if (rv[7]) {
                f16x8 v = *(const f16x8*)(&Ls[7][0] + cb);
                #pragma unroll
                for (int u = 0; u < 8; ++u) D[u] += (float)v[u];
            }
            if (rv[8]) {
                f16x8 v = *(const f16x8*)(&Ls[8][0] + cb);
                #pragma unroll
                for (int u = 0; u < 7; ++u) D[u] += (float)v[u + 1];
                if (cb + 8 < HW) D[7] += (float)Ls[8][cb + 8];
            }
        } else {
            #pragma unroll
            for (int u = 0; u < 8; ++u) {
                int q = q0 + u;
                if (q == 0) continue;
                int c = 4031 + q;
                float a2 = 0.f;
                if (rv[6]) a2 += (float)Ls[6][c - 1];
                if (rv[7]) a2 += (float)Ls[7][c];
                if (rv[8]) a2 += (float)Ls[8][c + 1];
                D[u] += a2;
            }
        }
    }

    float lv[8], sv[8];
    float lmax = -1e30f;
    #pragma unroll
    for (int u = 0; u < 8; ++u) {
        float2 m2 = md[q0 + u];
        float l = 10.f * D[u] * m2.x;
        lv[u] = l;
        sv[u] = m2.y;
        lmax = fmaxf(lmax, l);
    }
    #pragma unroll
    for (int off = 32; off > 0; off >>= 1)
        lmax = fmaxf(lmax, __shfl_xor(lmax, off, 64));
    int wv = tid >> 6;
    if ((tid & 63) == 0) wmax[wv] = lmax;
    __syncthreads();
    float M = wmax[0];
    #pragma unroll
    for (int w = 1; w < 8; ++w) M = fmaxf(M, wmax[w]);

    float ev[8];
    float ssum = 0.f;
    #pragma unroll
    for (int u = 0; u < 8; ++u) {
        ev[u] = expf(lv[u] - M);
        ssum += ev[u];
    }
    #pragma unroll
    for (int off = 32; off > 0; off >>= 1)
        ssum += __shfl_xor(ssum, off, 64);
    if ((tid & 63) == 0) wsum[wv] = ssum;
    __syncthreads();
    float tot = 0.f;
    #pragma unroll
    for (int w = 0; w < 8; ++w) tot += wsum[w];

    float inv = 1.f / tot;
    f16x8 outv;
    #pragma unroll
    for (int u = 0; u < 8; ++u)
        outv[u] = (_Float16)(ev[u] * inv * sv[u]);
    *(f16x8*)(V + (size_t)p * HW + q0) = outv;
}

// ---------------- WNT[n, j] = WN[j][n]  (plain transpose, f16) ----------------
__launch_bounds__(256)
__global__ void wnt_transpose(const _Float16* __restrict__ WN0, _Float16* __restrict__ WNT0) {
    const _Float16* WN = WN0 + (size_t)blockIdx.z * HW * KDIM;
    _Float16* WNT = WNT0 + (size_t)blockIdx.z * HW * HW;
    int bx = blockIdx.x;  // j-tile
    int by = blockIdx.y;  // n-tile
    int n0 = by * 64;
    __shared__ unsigned short tile[64][72];
    for (int c = threadIdx.x; c < 512; c += 256) {
        int l = c >> 3, seg = c & 7;
        int j = bx * 64 + l;
        uint4 v = *(const uint4*)(WN + (size_t)j * KDIM + n0 + seg * 8);
        *(uint4*)&tile[l][seg * 8] = v;
    }
    __syncthreads();
    for (int c = threadIdx.x; c < 512; c += 256) {
        int r = c >> 3, seg = c & 7;
        unsigned short tmp[8];
        #pragma unroll
        for (int u = 0; u < 8; ++u) tmp[u] = tile[seg * 8 + u][r];
        *(uint4*)(WNT + (size_t)(n0 + r) * HW + bx * 64 + seg * 8) = *(uint4*)tmp;
    }
}

// ---------------- fold C2T f16 into shift output, 8-pixel vectorized (r13-verified) ----------------
__launch_bounds__(256)
__global__ void fold_out_t(const _Float16* __restrict__ C2T0, float* __restrict__ out, int b0) {
    const _Float16* C2T = C2T0 + (size_t)blockIdx.z * HW * HW;
    float* outb = out + (size_t)(b0 + blockIdx.z) * COUT * HW;
    int c = blockIdx.x;
    const _Float16* base = C2T + (size_t)c * 9 * HW;
    int seg = blockIdx.y * 256 + threadIdx.x;   // 0..511
    int pix0 = seg * 8;
    int y = pix0 >> 6, x0 = pix0 & 63;
    float s[8] = {0.f, 0.f, 0.f, 0.f, 0.f, 0.f, 0.f, 0.f};
    #pragma unroll
    for (int dy = 0; dy < 3; ++dy) {
        int yy = y + 1 - dy;
        if ((unsigned)yy >= 64) continue;
        #pragma unroll
        for (int dx = 0; dx < 3; ++dx) {
            const _Float16* row = base + (size_t)(dy * 3 + dx) * HW + yy * 64;
            f16x8 v = *(const f16x8*)(row + x0);
            if (dx == 1) {
                #pragma unroll
                for (int u = 0; u < 8; ++u) s[u] += (float)v[u];
            } else if (dx == 0) {
                #pragma unroll
                for (int u = 0; u < 7; ++u) s[u] += (float)v[u + 1];
                if (x0 + 8 < 64) s[7] += (float)row[x0 + 8];
            } else {
                #pragma unroll
                for (int u = 1; u < 8; ++u) s[u] += (float)v[u - 1];
                if (x0 > 0) s[0] += (float)row[x0 - 1];
            }
        }
    }
    float* op = outb + (size_t)(CIN + c) * HW + pix0;
    f32x4 o0 = {s[0] * (1.f / 9.f), s[1] * (1.f / 9.f), s[2] * (1.f / 9.f), s[3] * (1.f / 9.f)};
    f32x4 o1 = {s[4] * (1.f / 9.f), s[5] * (1.f / 9.f), s[6] * (1.f / 9.f), s[7] * (1.f / 9.f)};
    *(f32x4*)(op) = o0;
    *(f32x4*)(op + 4) = o1;
}

extern "C" void kernel_launch(void* const* d_in, const int* in_sizes, int n_in,
                              void* d_out, int out_size, void* d_ws, size_t ws_size,
                              hipStream_t stream) {
    const float* x = (const float*)d_in[0];
    const float* mask = (const float*)d_in[1];
    const int* mask_thred = (const int*)d_in[3];
    float* out = (float*)d_out;

    // Fixed round-0 layout (172,032,000 B total), no ws_size branching.
    char* ws = (char*)d_ws;
    _Float16* P   = (_Float16*)(ws);                      // 2 x  9,437,184 B
    _Float16* WN  = (_Float16*)(ws + 18874368);           // 2 x  9,437,184 B
    _Float16* S   = (_Float16*)(ws + 37748736);           // 2 x 33,554,432 B (scores; dead after dconv)
    _Float16* R2  = (_Float16*)(ws + 104857600);          // 2 x 33,554,432 B (V lives here)
    float2*   md  = (float2*)(ws + 171966464);            // 2 x 32,768 B
    // lifetime-disjoint aliases (stream-ordered, per-z stride HW*HW):
    _Float16* V   = R2;                                   // dconv output (disjoint from S)
    _Float16* WNT = S;                                    // written AFTER dconv consumed S
    _Float16* C2T = S + (size_t)KDIM * HW;                // gemm2 output (disjoint from WNT per z)

    for (int pp = 0; pp < 2; ++pp) {
        int b0 = pp * 2;
        int copyN = (pp == 0) ? 2048 : 0;                 // copy done once, in pass 0's prep
        prep_fused<<<dim3(copyN + 2304 + 4096, 1, 2), 256, 0, stream>>>(
            x, mask, mask_thred, P, WN, md, (float4*)out, b0, copyN);
        // GEMM1: S[i][j] = sum_k P[i][k] WN[j][k], M=N=4096, K=1152 (8-phase 256^2, r4 variant)
        gemm1_8ph<<<dim3(256, 1, 2), 512, 131072, stream>>>(P, WN, S);
        dconv_softmax<<<dim3(HW, 1, 2), 512, 0, stream>>>(S, md, V);          // S -> V, LDS-staged
        wnt_transpose<<<dim3(64, KDIM / 64, 2), 256, 0, stream>>>(WN, WNT);   // S dead -> reuse region
        // GEMM2: C2T[n][p] = sum_q WNT[n][q] V[p][q], M=1152, N=4096, K=4096 (128x64 tile, 4.5 blk/CU)
        gemm2_f16_nt<<<dim3(64, KDIM / 128, 2), 256, 0, stream>>>(WNT, V, C2T, HW, HW);
        fold_out_t<<<dim3(CH, 2, 2), 256, 0, stream>>>(C2T, out, b0);
    }
}

// Round 16
// 671.615 us; speedup vs baseline: 1.2227x; 1.0492x over previous
//
#include <hip/hip_runtime.h>
#include <math.h>

#define H 64
#define W 64
#define HW 4096
#define CH 128
#define CIN 256
#define COUT 384
#define KDIM 1152
#define NB 4

typedef _Float16 f16x8 __attribute__((ext_vector_type(8)));
typedef float f32x4 __attribute__((ext_vector_type(4)));

__device__ __forceinline__ void gl_lds16(const _Float16* g, _Float16* l) {
    __builtin_amdgcn_global_load_lds(
        (const __attribute__((address_space(1))) unsigned int*)(g),
        (__attribute__((address_space(3))) unsigned int*)(l), 16, 0, 0);
}

// ---------------- fused prep: copy passthrough + im2col(P) + winn(WN,md), partitioned grid ----------------
// Block ranges (x): [0,copyN) copy; [copyN,copyN+2304) patches; [copyN+2304, +4096) winn. (r14-verified)
__global__ void prep_fused(const float* __restrict__ x, const float* __restrict__ mask,
                           const int* __restrict__ mask_thred_p,
                           _Float16* __restrict__ P, _Float16* __restrict__ WN,
                           float2* __restrict__ md, float4* __restrict__ outv4,
                           int b0, int copyN) {
    __shared__ float red4[4];
    int id = blockIdx.x;
    int z = blockIdx.z;

    if (id < copyN) {
        int idx = (id + z * copyN) * 256 + threadIdx.x;   // covers NB*CIN*HW/4 exactly (copyN=2048)
        if (idx < NB * CIN * HW / 4) {
            int b = idx / (CIN * HW / 4);
            int rem = idx - b * (CIN * HW / 4);
            outv4[(size_t)b * (COUT * HW / 4) + rem] = ((const float4*)x)[idx];
        }
        return;
    }
    id -= copyN;

    if (id < 2304) {
        int idx8 = id * 256 + threadIdx.x;                // < HW*144 = 589824
        const float* former = x + (size_t)(b0 + z) * CIN * HW;
        _Float16* Pz = P + (size_t)z * HW * KDIM;
        int slot = idx8 >> 12;          // 0..143
        int i = idx8 & 4095;
        int k0 = slot * 8;
        int iy = i >> 6, ix = i & 63;
        f16x8 v8;
        #pragma unroll
        for (int u = 0; u < 8; ++u) {
            int k = k0 + u;
            int c = k / 9, q = k - c * 9;     // wave-uniform
            int dy = q / 3, dx = q - dy * 3;
            int y = iy + dy - 1, xx = ix + dx - 1;
            float v = 0.f;
            if ((unsigned)y < H && (unsigned)xx < W) v = former[c * HW + y * W + xx];
            v8[u] = (_Float16)v;
        }
        *(f16x8*)(Pz + (size_t)i * KDIM + k0) = v8;
        return;
    }
    int j = id - 2304;                                    // 0..4095

    int b = b0 + z;
    const float* latter = x + (size_t)b * CIN * HW + (size_t)CH * HW;
    const float* maskb = mask + (size_t)b * HW;
    _Float16* WNz = WN + (size_t)z * HW * KDIM;
    float2* mdz = md + (size_t)z * HW;
    int y0 = j >> 6, x0 = j & 63;
    float vals[8];
    float ss = 0.f;
    int k0 = threadIdx.x * 8;
    bool act = (threadIdx.x < 144);
    if (act) {
        #pragma unroll
        for (int u = 0; u < 8; ++u) {
            int k = k0 + u;
            int c = k / 9, q = k - c * 9;
            int dy = q / 3, dx = q - dy * 3;
            int y = y0 + dy - 1, xx = x0 + dx - 1;
            float v = 0.f;
            if ((unsigned)y < H && (unsigned)xx < W) v = latter[c * HW + y * W + xx];
            vals[u] = v;
            ss += v * v;
        }
    }
    #pragma unroll
    for (int off = 32; off > 0; off >>= 1)
        ss += __shfl_xor(ss, off, 64);
    int wv = threadIdx.x >> 6;
    if ((threadIdx.x & 63) == 0) red4[wv] = ss;
    __syncthreads();
    float tot = red4[0] + red4[1] + red4[2] + red4[3];
    float d = fmaxf(sqrtf(tot), 1e-4f);
    float inv = 1.f / d;
    if (act) {
        f16x8 w8;
        #pragma unroll
        for (int u = 0; u < 8; ++u) w8[u] = (_Float16)(vals[u] * inv);
        *(f16x8*)(WNz + (size_t)j * KDIM + k0) = w8;
    }
    if (threadIdx.x == 0) {
        float s = 0.f;
        for (int q = 0; q < 9; ++q) {
            int dy = q / 3, dx = q - dy * 3;
            int y = y0 + dy - 1, xx = x0 + dx - 1;
            if ((unsigned)y < H && (unsigned)xx < W) s += maskb[y * W + xx];
        }
        float mmean = s / 9.f;
        float thr = (float)mask_thred_p[0] / 9.f;
        float m = (mmean <= thr) ? 1.f : 0.f;
        mdz[j] = make_float2(m, m * d);
    }
}

// ---------------- GEMM1: 256x256 tile, BK=64, 8-phase counted-vmcnt (r4-measured-best variant) ----------------
__launch_bounds__(512, 2)
__global__ void gemm1_8ph(const _Float16* __restrict__ A0, const _Float16* __restrict__ B0,
                          _Float16* __restrict__ C0) {
    const int K = KDIM;
    const int NT = KDIM / 64;     // 18 K-tiles
    const _Float16* A = A0 + (size_t)blockIdx.z * HW * KDIM;
    const _Float16* B = B0 + (size_t)blockIdx.z * HW * KDIM;
    _Float16* C = C0 + (size_t)blockIdx.z * HW * HW;

    extern __shared__ _Float16 lds[];
    _Float16* As = lds;            // [2][2][128][64]
    _Float16* Bs = lds + 32768;    // [2][2][128][64]

    int tid = threadIdx.x;
    int wave = tid >> 6, lane = tid & 63;
    int quad = lane >> 4, lr = lane & 15;
    int wr = wave >> 2, wc = wave & 3;

    int lin = blockIdx.x;
    int wg = (lin & 7) * 32 + (lin >> 3);
    int i0 = (wg >> 4) * 256, j0 = (wg & 15) * 256;

    const _Float16* Ab = A + (size_t)i0 * K;
    const _Float16* Bb = B + (size_t)j0 * K;

    f32x4 acc[8][4];
    #pragma unroll
    for (int f = 0; f < 8; ++f)
        #pragma unroll
        for (int g = 0; g < 4; ++g) acc[f][g] = (f32x4){0.f, 0.f, 0.f, 0.f};

    auto stageA = [&](int d, int h, int v) {
        const _Float16* g = Ab + (size_t)(h * 128) * K + v * 64;
        _Float16* dst = As + d * 16384 + h * 8192;
        #pragma unroll
        for (int l = 0; l < 2; ++l) {
            int slot = tid + l * 512;
            int row = slot >> 3;
            gl_lds16(g + (size_t)row * K + (((slot & 7) ^ (row & 7)) << 3), dst + slot * 8);
        }
    };
    auto stageB = [&](int d, int h, int v) {
        const _Float16* g = Bb + (size_t)(h * 128) * K + v * 64;
        _Float16* dst = Bs + d * 16384 + h * 8192;
        #pragma unroll
        for (int l = 0; l < 2; ++l) {
            int slot = tid + l * 512;
            int row = slot >> 3;
            gl_lds16(g + (size_t)row * K + (((slot & 7) ^ (row & 7)) << 3), dst + slot * 8);
        }
    };

    stageA(0, 0, 0); stageB(0, 1, 0); stageA(0, 1, 0); stageB(0, 0, 0);
    stageA(1, 0, 1); stageB(1, 1, 1);
    asm volatile("s_waitcnt vmcnt(4)" ::: "memory");
    __builtin_amdgcn_s_barrier();
    __builtin_amdgcn_sched_barrier(0);

    for (int u = 0; u < NT; ++u) {
        int d = u & 1;
        #pragma unroll
        for (int ph = 0; ph < 4; ++ph) {
            const int mh = ph >> 1;
            const int nh = (ph == 1 || ph == 2) ? 1 : 0;
            const _Float16* Ah = As + d * 16384 + mh * 8192;
            const _Float16* Bh = Bs + d * 16384 + nh * 8192;
            f16x8 af[4][2], bfr[2][2];
            #pragma unroll
            for (int f = 0; f < 4; ++f)
                #pragma unroll
                for (int ks = 0; ks < 2; ++ks)
                    af[f][ks] = *(const f16x8*)(Ah + (wr * 16 + f * 32 + lr) * 64 +
                                                ((((ks << 2) | quad) ^ (lr & 7)) << 3));
            #pragma unroll
            for (int g = 0; g < 2; ++g)
                #pragma unroll
                for (int ks = 0; ks < 2; ++ks)
                    bfr[g][ks] = *(const f16x8*)(Bh + (wc * 16 + g * 64 + lr) * 64 +
                                                 ((((ks << 2) | quad) ^ (lr & 7)) << 3));
            if (ph == 0)      { if (u + 1 < NT) stageA(d ^ 1, 1, u + 1); }
            else if (ph == 1) { if (u + 1 < NT) stageB(d ^ 1, 0, u + 1); }
            else if (ph == 2) { if (u + 2 < NT) stageA(d, 0, u + 2); }
            else              { if (u + 2 < NT) stageB(d, 1, u + 2); }

            __builtin_amdgcn_s_barrier();
            __builtin_amdgcn_s_setprio(1);
            #pragma unroll
            for (int f = 0; f < 4; ++f)
                #pragma unroll
                for (int g = 0; g < 2; ++g)
                    #pragma unroll
                    for (int ks = 0; ks < 2; ++ks)
                        acc[mh * 4 + f][nh * 2 + g] = __builtin_amdgcn_mfma_f32_16x16x32_f16(
                            af[f][ks], bfr[g][ks], acc[mh * 4 + f][nh * 2 + g], 0, 0, 0);
            __builtin_amdgcn_s_setprio(0);

            if (ph == 3) {
                if (u + 2 < NT)      asm volatile("s_waitcnt vmcnt(4)" ::: "memory");
                else if (u + 1 < NT) asm volatile("s_waitcnt vmcnt(0)" ::: "memory");
                __builtin_amdgcn_sched_barrier(0);
            }
            __builtin_amdgcn_s_barrier();
        }
    }

    #pragma unroll
    for (int f = 0; f < 8; ++f) {
        #pragma unroll
        for (int r = 0; r < 4; ++r) {
            int row = i0 + wr * 16 + f * 32 + quad * 4 + r;
            _Float16* Cr = C + (size_t)row * HW + j0 + wc * 16 + lr;
            #pragma unroll
            for (int g = 0; g < 4; ++g)
                Cr[g * 64] = (_Float16)acc[f][g][r];
        }
    }
}

// ---------------- GEMM2: MFMA f16 NT, 128(M)x64(N) tile, BK=64, full K, f16 out ----------------
// r14-measured-best geometry (1152 blocks z=2). v2: explicit per-z A-stride (sAz) so A can live
// in the P region (stride KDIM*HW) while B/C keep HW*HW strides.
__launch_bounds__(256)
__global__ void gemm2_f16_nt(const _Float16* __restrict__ A0, const _Float16* __restrict__ B0,
                             _Float16* __restrict__ C0, int K, int ldc, unsigned long long sAz) {
    const _Float16* A = A0 + (size_t)blockIdx.z * sAz;       // WNT_z (P region)
    const _Float16* B = B0 + (size_t)blockIdx.z * HW * HW;   // V_z
    _Float16* C = C0 + (size_t)blockIdx.z * HW * HW;         // C2T_z
    __shared__ _Float16 As[128 * 64];
    __shared__ _Float16 Bs[64 * 64];
    int tid = threadIdx.x;
    int wave = tid >> 6, lane = tid & 63;
    int quad = lane >> 4, lr = lane & 15;
    int wr = wave >> 1, wc = wave & 1;
    int i0 = blockIdx.y * 128, j0 = blockIdx.x * 64;

    int r0 = tid >> 3;
    int lk = ((tid & 7) ^ ((tid >> 3) & 7)) * 8;

    f32x4 acc[4][2];
    #pragma unroll
    for (int a = 0; a < 4; ++a)
        #pragma unroll
        for (int b = 0; b < 2; ++b) acc[a][b] = (f32x4){0.f, 0.f, 0.f, 0.f};

    const _Float16* Ab = A + (size_t)i0 * K;
    const _Float16* Bb = B + (size_t)j0 * K;

    int ra[4][2], rb[2][2];
    #pragma unroll
    for (int t = 0; t < 4; ++t) {
        int rowA = wr * 64 + t * 16 + lr;
        #pragma unroll
        for (int s = 0; s < 2; ++s)
            ra[t][s] = rowA * 64 + (((quad + 4 * s) ^ (lr & 7)) * 8);
    }
    #pragma unroll
    for (int t = 0; t < 2; ++t) {
        int rowB = wc * 32 + t * 16 + lr;
        #pragma unroll
        for (int s = 0; s < 2; ++s)
            rb[t][s] = rowB * 64 + (((quad + 4 * s) ^ (lr & 7)) * 8);
    }

    for (int k0 = 0; k0 < K; k0 += 64) {
        __syncthreads();
        #pragma unroll
        for (int j = 0; j < 4; ++j) {
            int row = r0 + j * 32;
            gl_lds16(Ab + (size_t)row * K + k0 + lk, As + (tid + j * 256) * 8);
        }
        #pragma unroll
        for (int j = 0; j < 2; ++j) {
            int row = r0 + j * 32;
            gl_lds16(Bb + (size_t)row * K + k0 + lk, Bs + (tid + j * 256) * 8);
        }
        __syncthreads();
        #pragma unroll
        for (int s = 0; s < 2; ++s) {
            f16x8 af[4], bfr[2];
            #pragma unroll
            for (int mi = 0; mi < 4; ++mi) af[mi] = *(const f16x8*)(As + ra[mi][s]);
            #pragma unroll
            for (int ni = 0; ni < 2; ++ni) bfr[ni] = *(const f16x8*)(Bs + rb[ni][s]);
            #pragma unroll
            for (int mi = 0; mi < 4; ++mi)
                #pragma unroll
                for (int ni = 0; ni < 2; ++ni)
                    acc[mi][ni] = __builtin_amdgcn_mfma_f32_16x16x32_f16(af[mi], bfr[ni], acc[mi][ni], 0, 0, 0);
        }
    }

    #pragma unroll
    for (int mi = 0; mi < 4; ++mi) {
        #pragma unroll
        for (int r = 0; r < 4; ++r) {
            int row = i0 + wr * 64 + mi * 16 + quad * 4 + r;
            _Float16* Cr = C + (size_t)row * ldc + j0 + wc * 32 + lr;
            #pragma unroll
            for (int ni = 0; ni < 2; ++ni)
                Cr[ni * 16] = (_Float16)acc[mi][ni][r];
        }
    }
}

// ---------------- fused: dconv+softmax (blocks [0,HW)) + WNT transpose (blocks [HW,HW+1152)) ----------------
// Race audit: dconv reads S,md writes V; wnt reads WN writes WNT (P region, per-z stride KDIM*HW).
// P is dead after gemm1 (stream-ordered). All four regions disjoint -> race-free.
// LDS is a UNION (single 73,728 B buffer) so dconv keeps 2 blocks/CU.
__launch_bounds__(512)
__global__ void dconv_wnt(const _Float16* __restrict__ S0, const float2* __restrict__ md0,
                          _Float16* __restrict__ V0,
                          const _Float16* __restrict__ WN0, _Float16* __restrict__ WNT0) {
    __shared__ char sbuf[9 * HW * sizeof(_Float16)];   // 73,728 B union
    __shared__ float wmax[8], wsum[8];
    int bid = blockIdx.x;

    if (bid >= HW) {
        // ---- WNT[n, j] = WN[j][n] tile; per-z stride KDIM*HW (P region holds exactly 2 of these) ----
        int t = bid - HW;                 // 0..1151
        int bx = t & 63, by = t >> 6;     // 64 j-tiles x 18 n-tiles
        const _Float16* WN = WN0 + (size_t)blockIdx.z * HW * KDIM;
        _Float16* WNT = WNT0 + (size_t)blockIdx.z * KDIM * HW;
        int n0 = by * 64;
        unsigned short (*tile)[72] = (unsigned short (*)[72])sbuf;   // 9,216 B <= union
        {
            int c = threadIdx.x;          // 0..511, one slot each (same coverage as r13's 2x256)
            int l = c >> 3, seg = c & 7;
            int j = bx * 64 + l;
            uint4 v = *(const uint4*)(WN + (size_t)j * KDIM + n0 + seg * 8);
            *(uint4*)&tile[l][seg * 8] = v;
        }
        __syncthreads();
        {
            int c = threadIdx.x;
            int r = c >> 3, seg = c & 7;
            unsigned short tmp[8];
            #pragma unroll
            for (int u = 0; u < 8; ++u) tmp[u] = tile[seg * 8 + u][r];
            *(uint4*)(WNT + (size_t)(n0 + r) * HW + bx * 64 + seg * 8) = *(uint4*)tmp;
        }
        return;
    }

    // ---- dconv_softmax body (r3/r4-verified, unchanged semantics) ----
    _Float16 (*Ls)[HW] = (_Float16 (*)[HW])sbuf;
    const _Float16* S = S0 + (size_t)blockIdx.z * HW * HW;
    const float2* md = md0 + (size_t)blockIdx.z * HW;
    _Float16* V = V0 + (size_t)blockIdx.z * HW * HW;
    int p = (bid & 7) * 512 + (bid >> 3);   // XCD-contiguous p ranges
    int tid = threadIdx.x;
    int q0 = tid * 8;

    const int P1 = ((p >> 6) < 63) ? (p + 64) : ((p & 63) + 1);   // valid iff p != 4095
    const int P0 = ((p >> 6) > 0) ? (p - 64) : (4031 + (p & 63)); // valid iff p != 0
    const bool gv1 = (p != 4095), gv2 = (p != 0);

    int rows[9];
    bool rv[9];
    rows[0] = p - 1;  rows[1] = p;  rows[2] = p + 1;
    rows[3] = P1 - 1; rows[4] = P1; rows[5] = P1 + 1;
    rows[6] = P0 - 1; rows[7] = P0; rows[8] = P0 + 1;
    rv[0] = ((unsigned)(p - 1) < HW);
    rv[1] = true;
    rv[2] = ((unsigned)(p + 1) < HW);
    rv[3] = gv1 && ((unsigned)(P1 - 1) < HW);
    rv[4] = gv1;
    rv[5] = gv1 && ((unsigned)(P1 + 1) < HW);
    rv[6] = gv2 && ((unsigned)(P0 - 1) < HW);
    rv[7] = gv2;
    rv[8] = gv2 && ((unsigned)(P0 + 1) < HW);

    #pragma unroll
    for (int s = 0; s < 9; ++s) {
        if (rv[s])
            gl_lds16(S + (size_t)rows[s] * HW + q0, &Ls[s][0] + q0);
    }
    __syncthreads();   // drains vmcnt before barrier

    float D[8] = {0.f, 0.f, 0.f, 0.f, 0.f, 0.f, 0.f, 0.f};

    {
        const int cb = q0;
        if (rv[0]) {
            f16x8 v = *(const f16x8*)(&Ls[0][0] + cb);
            #pragma unroll
            for (int u = 1; u < 8; ++u) D[u] += (float)v[u - 1];
            if (cb > 0) D[0] += (float)Ls[0][cb - 1];
        }
        {
            f16x8 v = *(const f16x8*)(&Ls[1][0] + cb);
            #pragma unroll
            for (int u = 0; u < 8; ++u) D[u] += (float)v[u];
        }
        if (rv[2]) {
            f16x8 v = *(const f16x8*)(&Ls[2][0] + cb);
            #pragma unroll
            for (int u = 0; u < 7; ++u) D[u] += (float)v[u + 1];
            if (cb + 8 < HW) D[7] += (float)Ls[2][cb + 8];
        }
    }

    if (gv1) {
        if ((tid >> 3) != 63) {
            const int cb = q0 + 64;
            if (rv[3]) {
                f16x8 v = *(const f16x8*)(&Ls[3][0] + cb);
                #pragma unroll
                for (int u = 1; u < 8; ++u) D[u] += (float)v[u - 1];
                D[0] += (float)Ls[3][cb - 1];
            }
            if (rv[4]) {
                f16x8 v = *(const f16x8*)(&Ls[4][0] + cb);
                #pragma unroll
                for (int u = 0; u < 8; ++u) D[u] += (float)v[u];
            }
            if (rv[5]) {
                f16x8 v = *(const f16x8*)(&Ls[5][0] + cb);
                #pragma unroll
                for (int u = 0; u < 7; ++u) D[u] += (float)v[u + 1];
                if (cb + 8 < HW) D[7] += (float)Ls[5][cb + 8];
            }
        } else {
            #pragma unroll
            for (int u = 0; u < 8; ++u) {
                int q = q0 + u;
                if (q == 4095) continue;
                int c = (q & 63) + 1;
                float a2 = 0.f;
                if (rv[3]) a2 += (float)Ls[3][c - 1];
                if (rv[4]) a2 += (float)Ls[4][c];
                if (rv[5]) a2 += (float)Ls[5][c + 1];
                D[u] += a2;
            }
        }
    }

    if (gv2) {
        if ((tid >> 3) != 0) {
            const int cb = q0 - 64;
            if (rv[6]) {
                f16x8 v = *(const f16x8*)(&Ls[6][0] + cb);
                #pragma unroll
                for (int u = 1; u < 8; ++u) D[u] += (float)v[u - 1];
                if (cb > 0) D[0] += (float)Ls[6][cb - 1];
            }
            if (rv[7]) {
                f16x8 v = *(const f16x8*)(&Ls[7][0] + cb);
                #pragma unroll
                for (int u = 0; u < 8; ++u) D[u] += (float)v[u];
            }
            if (rv[8]) {
                f16x8 v = *(const f16x8*)(&Ls[8][0] + cb);
                #pragma unroll
                for (int u = 0; u < 7; ++u) D[u] += (float)v[u + 1];
                if (cb + 8 < HW) D[7] += (float)Ls[8][cb + 8];
            }
        } else {
            #pragma unroll
            for (int u = 0; u < 8; ++u) {
                int q = q0 + u;
                if (q == 0) continue;
                int c = 4031 + q;
                float a2 = 0.f;
                if (rv[6]) a2 += (float)Ls[6][c - 1];
                if (rv[7]) a2 += (float)Ls[7][c];
                if (rv[8]) a2 += (float)Ls[8][c + 1];
                D[u] += a2;
            }
        }
    }

    float lv[8], sv[8];
    float lmax = -1e30f;
    #pragma unroll
    for (int u = 0; u < 8; ++u) {
        float2 m2 = md[q0 + u];
        float l = 10.f * D[u] * m2.x;
        lv[u] = l;
        sv[u] = m2.y;
        lmax = fmaxf(lmax, l);
    }
    #pragma unroll
    for (int off = 32; off > 0; off >>= 1)
        lmax = fmaxf(lmax, __shfl_xor(lmax, off, 64));
    int wv = tid >> 6;
    if ((tid & 63) == 0) wmax[wv] = lmax;
    __syncthreads();
    float M = wmax[0];
    #pragma unroll
    for (int w = 1; w < 8; ++w) M = fmaxf(M, wmax[w]);

    float ev[8];
    float ssum = 0.f;
    #pragma unroll
    for (int u = 0; u < 8; ++u) {
        ev[u] = expf(lv[u] - M);
        ssum += ev[u];
    }
    #pragma unroll
    for (int off = 32; off > 0; off >>= 1)
        ssum += __shfl_xor(ssum, off, 64);
    if ((tid & 63) == 0) wsum[wv] = ssum;
    __syncthreads();
    float tot = 0.f;
    #pragma unroll
    for (int w = 0; w < 8; ++w) tot += wsum[w];

    float inv = 1.f / tot;
    f16x8 outv;
    #pragma unroll
    for (int u = 0; u < 8; ++u)
        outv[u] = (_Float16)(ev[u] * inv * sv[u]);
    *(f16x8*)(V + (size_t)p * HW + q0) = outv;
}

// ---------------- fold C2T f16 into shift output, 8-pixel vectorized (r13-verified) ----------------
__launch_bounds__(256)
__global__ void fold_out_t(const _Float16* __restrict__ C2T0, float* __restrict__ out, int b0) {
    const _Float16* C2T = C2T0 + (size_t)blockIdx.z * HW * HW;
    float* outb = out + (size_t)(b0 + blockIdx.z) * COUT * HW;
    int c = blockIdx.x;
    const _Float16* base = C2T + (size_t)c * 9 * HW;
    int seg = blockIdx.y * 256 + threadIdx.x;   // 0..511
    int pix0 = seg * 8;
    int y = pix0 >> 6, x0 = pix0 & 63;
    float s[8] = {0.f, 0.f, 0.f, 0.f, 0.f, 0.f, 0.f, 0.f};
    #pragma unroll
    for (int dy = 0; dy < 3; ++dy) {
        int yy = y + 1 - dy;
        if ((unsigned)yy >= 64) continue;
        #pragma unroll
        for (int dx = 0; dx < 3; ++dx) {
            const _Float16* row = base + (size_t)(dy * 3 + dx) * HW + yy * 64;
            f16x8 v = *(const f16x8*)(row + x0);
            if (dx == 1) {
                #pragma unroll
                for (int u = 0; u < 8; ++u) s[u] += (float)v[u];
            } else if (dx == 0) {
                #pragma unroll
                for (int u = 0; u < 7; ++u) s[u] += (float)v[u + 1];
                if (x0 + 8 < 64) s[7] += (float)row[x0 + 8];
            } else {
                #pragma unroll
                for (int u = 1; u < 8; ++u) s[u] += (float)v[u - 1];
                if (x0 > 0) s[0] += (float)row[x0 - 1];
            }
        }
    }
    float* op = outb + (size_t)(CIN + c) * HW + pix0;
    f32x4 o0 = {s[0] * (1.f / 9.f), s[1] * (1.f / 9.f), s[2] * (1.f / 9.f), s[3] * (1.f / 9.f)};
    f32x4 o1 = {s[4] * (1.f / 9.f), s[5] * (1.f / 9.f), s[6] * (1.f / 9.f), s[7] * (1.f / 9.f)};
    *(f32x4*)(op) = o0;
    *(f32x4*)(op + 4) = o1;
}

extern "C" void kernel_launch(void* const* d_in, const int* in_sizes, int n_in,
                              void* d_out, int out_size, void* d_ws, size_t ws_size,
                              hipStream_t stream) {
    const float* x = (const float*)d_in[0];
    const float* mask = (const float*)d_in[1];
    const int* mask_thred = (const int*)d_in[3];
    float* out = (float*)d_out;

    // Fixed round-0 layout (172,032,000 B total), no ws_size branching.
    char* ws = (char*)d_ws;
    _Float16* P   = (_Float16*)(ws);                      // 2 x KDIM*HW f16 (im2col; dead after gemm1)
    _Float16* WN  = (_Float16*)(ws + 18874368);           // 2 x HW*KDIM f16
    _Float16* S   = (_Float16*)(ws + 37748736);           // 2 x HW*HW f16 (scores; dead after dconv_wnt)
    _Float16* R2  = (_Float16*)(ws + 104857600);          // 2 x HW*HW f16 (V lives here)
    float2*   md  = (float2*)(ws + 171966464);            // 2 x HW float2
    // lifetime-disjoint aliases (stream-ordered):
    _Float16* V     = R2;                                 // dconv output (disjoint from S)
    _Float16* WNT_p = P;                                  // wnt output in dead P region, per-z stride KDIM*HW
                                                          //  (2 x KDIM*HW fits P exactly; disjoint from S/V/WN/md)
    _Float16* C2T   = S + (size_t)KDIM * HW;              // gemm2 output in dead S region, per-z stride HW*HW
                                                          //  (z=1 ends at KDIM*HW + HW*HW + KDIM*HW < 2*HW*HW)

    for (int pp = 0; pp < 2; ++pp) {
        int b0 = pp * 2;
        int copyN = (pp == 0) ? 2048 : 0;                 // copy done once, in pass 0's prep
        prep_fused<<<dim3(copyN + 2304 + 4096, 1, 2), 256, 0, stream>>>(
            x, mask, mask_thred, P, WN, md, (float4*)out, b0, copyN);
        // GEMM1: S[i][j] = sum_k P[i][k] WN[j][k] (consumes P -> P region free afterwards)
        gemm1_8ph<<<dim3(256, 1, 2), 512, 131072, stream>>>(P, WN, S);
        // fused: dconv (S,md -> V) + wnt (WN -> WNT in P region)
        dconv_wnt<<<dim3(HW + 1152, 1, 2), 512, 0, stream>>>(S, md, V, WN, WNT_p);
        // GEMM2: C2T[n][p] = sum_q WNT[n][q] V[p][q]; A-stride KDIM*HW (P region), B/C stride HW*HW
        gemm2_f16_nt<<<dim3(64, KDIM / 128, 2), 256, 0, stream>>>(
            WNT_p, V, C2T, HW, HW, (unsigned long long)KDIM * HW);
        fold_out_t<<<dim3(CH, 2, 2), 256, 0, stream>>>(C2T, out, b0);
    }
}